// Round 8
// baseline (1442.462 us; speedup 1.0000x reference)
//
#include <hip/hip_runtime.h>
#include <math.h>

// Model dims: H=512 D=128 L=8 T=64 W=240 CTX=60 NSTEPS=30

typedef __attribute__((ext_vector_type(8))) short short8;
typedef __attribute__((ext_vector_type(4))) float floatx4;
typedef unsigned long long ull;

__device__ __forceinline__ float sigf(float x) { return 1.f / (1.f + __expf(-x)); }
__device__ __forceinline__ float tanh_f(float x) {
    float e = __expf(2.f * x);
    return 1.f - 2.f / (e + 1.f);
}
__device__ __forceinline__ unsigned short f2b(float x) {   // fp32 -> bf16 RNE
    unsigned u = __float_as_uint(x);
    unsigned r = (u + 0x7FFFu + ((u >> 16) & 1u)) >> 16;
    return (unsigned short)r;
}

// RELAXED agent-scope atomics only (acquire/release emit buffer_inv/wbl2 on
// gfx950 and trash the XCD L2). Cross-block payloads are {epoch|data} ull
// words polled directly, batch-polled.
// R12: the encoder exchange gets an XCD-LOCAL FAST PATH. Group remap
// (xcd=bid&7, fg=xcd*2+(k>>4)) makes each 16-block exchange group XCD-pure
// under the round-robin block->XCD heuristic; producers dual-publish every
// word (volatile plain store -> own XCD L2 [CDNA L1 is write-through, volatile
// loads bypass L1], agent store -> MALL); consumers alternate fast(L2) and
// slow(MALL) polls, accepting either epoch match. Correctness NEVER depends
// on the mapping (G16): any epoch-matched word from either buffer is the
// value; if the heuristic/volatile assumption fails, the slow path is exactly
// the R9-R11 exchange. Mutual-gating stability argument applies to both
// buffers identically.
__device__ __forceinline__ float gld(const float* p) {
    return __hip_atomic_load(p, __ATOMIC_RELAXED, __HIP_MEMORY_SCOPE_AGENT);
}
__device__ __forceinline__ void gst(float* p, float v) {
    __hip_atomic_store(p, v, __ATOMIC_RELAXED, __HIP_MEMORY_SCOPE_AGENT);
}
__device__ __forceinline__ ull gldll(const ull* p) {
    return __hip_atomic_load(p, __ATOMIC_RELAXED, __HIP_MEMORY_SCOPE_AGENT);
}
__device__ __forceinline__ void gstll(ull* p, ull v) {
    __hip_atomic_store(p, v, __ATOMIC_RELAXED, __HIP_MEMORY_SCOPE_AGENT);
}
__device__ __forceinline__ ull packfe(float d, int ep) {
    return ((ull)(unsigned)ep << 32) | (ull)__float_as_uint(d);
}
__device__ __forceinline__ float lowf(ull v) { return __uint_as_float((unsigned)v); }

// ---------------------------------------------------------------------------
// init: zero [fastF(245760f) | hbufF(245760f) | hp1 | hp2 | hdec] = 501760 f
// ---------------------------------------------------------------------------
__global__ void init_k(float* __restrict__ ws) {
    for (int i = blockIdx.x * blockDim.x + threadIdx.x; i < 501760; i += gridDim.x * blockDim.x)
        ws[i] = 0.f;
}

// ---------------------------------------------------------------------------
// Encoder, ONE persistent launch, 64 steps, bf16 MFMA.
// R12: grid 256; XCD-pure groups; dual-path h exchange (see header).
// ---------------------------------------------------------------------------
__global__ void __launch_bounds__(256, 1) enc_all(
    const float* __restrict__ data,
    const float* __restrict__ Wih, const float* __restrict__ Whh,
    const float* __restrict__ bih, const float* __restrict__ bhh,
    ull* __restrict__ fastF,        // [2][15][4096] {epoch|bf16x2}, L2 fast path
    ull* __restrict__ hbufF,        // [2][15][4096] {epoch|bf16x2}, MALL path
    float* __restrict__ henc)       // [240][512] fp32 final h
{
    __shared__ short act2[20 * 64 * 8];
    __shared__ float gw[4][640];
    __shared__ float cs[512];
    __shared__ short hw[4][16][8];
    __shared__ float biasL[4][4][8];

    const int tid = threadIdx.x;
    // XCD-pure group remap: xcd = bid&7 (round-robin heuristic), 32 blocks/XCD
    // = 2 groups of 16. Group fg in [0,16); fg==15 idles (grid 256 > 240).
    const int xcd = blockIdx.x & 7, kk = blockIdx.x >> 3;
    const int fg = xcd * 2 + (kk >> 4), ds = kk & 15;
    if (fg >= 15) return;

    const int w = tid >> 6, lane = tid & 63;
    const int n = lane & 15, q = lane >> 4;

    short8 bfrag[2][20];
#pragma unroll
    for (int nt = 0; nt < 2; ++nt) {
        int rr = nt * 16 + n;
        int g = rr >> 3, dp = rr & 7;
        int grow = g * 512 + ds * 32 + w * 8 + dp;
#pragma unroll
        for (int kt = 0; kt < 20; ++kt) {
            int k0 = kt * 32 + q * 8;
            const float* src = (k0 < 512) ? (Whh + (size_t)grow * 512 + k0)
                                          : (Wih + (size_t)grow * 128 + (k0 - 512));
            float4 lo = *(const float4*)src;
            float4 hi = *(const float4*)(src + 4);
            short8 bf;
            bf[0] = (short)f2b(lo.x); bf[1] = (short)f2b(lo.y);
            bf[2] = (short)f2b(lo.z); bf[3] = (short)f2b(lo.w);
            bf[4] = (short)f2b(hi.x); bf[5] = (short)f2b(hi.y);
            bf[6] = (short)f2b(hi.z); bf[7] = (short)f2b(hi.w);
            bfrag[nt][kt] = bf;
        }
    }
    if (tid < 128) {
        int w2 = tid >> 5, rr = tid & 31;
        int g = rr >> 3, dp = rr & 7;
        int grow = g * 512 + ds * 32 + w2 * 8 + dp;
        biasL[w2][g][dp] = bih[grow] + bhh[grow];
    }
    for (int i = tid; i < 512; i += 256) cs[i] = 0.f;
    __syncthreads();

    unsigned* a2u = (unsigned*)act2;

    for (int t = 0; t < 64; ++t) {
        // x prefetch FIRST: global loads issue, latency hides under the h poll
        const int kt2 = tid >> 6, l2 = tid & 63, f2v = l2 & 15, q2 = l2 >> 4;
        const float* xs = data + ((size_t)t * 240 + fg * 16 + f2v) * 128 + kt2 * 32 + q2 * 8;
        float4 lo = *(const float4*)xs;
        float4 hi = *(const float4*)(xs + 4);

        // h gather: dual-path batch poll of 16 {epoch|bf16x2} words.
        {
            const size_t goff = (size_t)((t & 1) * 15 + fg) * 4096;
            const ull* fsrc = fastF + goff;
            const ull* ssrc = hbufF + goff;
            ull v[16];
            for (;;) {
                bool ok = true;          // fast: XCD-L2 (volatile bypasses L1)
#pragma unroll
                for (int k2 = 0; k2 < 16; ++k2) {
                    v[k2] = *(volatile const ull*)(fsrc + tid + 256 * k2);
                    ok &= ((int)(v[k2] >> 32) == t);
                }
                if (ok) break;
                ok = true;               // slow: MALL (agent scope)
#pragma unroll
                for (int k2 = 0; k2 < 16; ++k2) {
                    v[k2] = gldll(ssrc + tid + 256 * k2);
                    ok &= ((int)(v[k2] >> 32) == t);
                }
                if (ok) break;
                __builtin_amdgcn_s_sleep(1);
            }
#pragma unroll
            for (int k2 = 0; k2 < 16; ++k2)
                a2u[tid + 256 * k2] = (unsigned)v[k2];
        }
        {
            short8 xp;
            xp[0] = (short)f2b(lo.x); xp[1] = (short)f2b(lo.y);
            xp[2] = (short)f2b(lo.z); xp[3] = (short)f2b(lo.w);
            xp[4] = (short)f2b(hi.x); xp[5] = (short)f2b(hi.y);
            xp[6] = (short)f2b(hi.z); xp[7] = (short)f2b(hi.w);
            *(short8*)&act2[((16 + kt2) * 64 + l2) * 8] = xp;
        }
        __syncthreads();

        floatx4 acc0 = {0.f, 0.f, 0.f, 0.f};
        floatx4 acc1 = {0.f, 0.f, 0.f, 0.f};
#pragma unroll
        for (int kt = 0; kt < 20; ++kt) {
            short8 a = *(short8*)&act2[(kt * 64 + lane) * 8];
            acc0 = __builtin_amdgcn_mfma_f32_16x16x32_bf16(a, bfrag[0][kt], acc0, 0, 0, 0);
            acc1 = __builtin_amdgcn_mfma_f32_16x16x32_bf16(a, bfrag[1][kt], acc1, 0, 0, 0);
        }
        *(floatx4*)&gw[w][(0 * 16 + n) * 20 + 4 * q] = acc0;
        *(floatx4*)&gw[w][(1 * 16 + n) * 20 + 4 * q] = acc1;

        int nb = (t + 1) & 1;
#pragma unroll
        for (int it = 0; it < 2; ++it) {
            int f = lane & 15, dp = q + 4 * it;
            float gi = gw[w][(0 * 8 + dp) * 20 + f] + biasL[w][0][dp];
            float gf = gw[w][(1 * 8 + dp) * 20 + f] + biasL[w][1][dp];
            float gg = gw[w][(2 * 8 + dp) * 20 + f] + biasL[w][2][dp];
            float go = gw[w][(3 * 8 + dp) * 20 + f] + biasL[w][3][dp];
            int ci = f * 32 + w * 8 + dp;
            float cc = cs[ci];
            float cn = sigf(gf) * cc + sigf(gi) * tanh_f(gg);
            float hn = sigf(go) * tanh_f(cn);
            cs[ci] = cn;
            hw[w][f][dp] = (short)f2b(hn);
            if (t == 63)
                gst(&henc[(size_t)(fg * 16 + f) * 512 + ds * 32 + w * 8 + dp], hn);
        }
        if (lane < 16) {
            const unsigned* hwu = (const unsigned*)&hw[w][lane][0];
            size_t off = (size_t)(nb * 15 + fg) * 4096 + (ds * 64 + w * 16 + lane) * 4;
            ull* fdst = fastF + off;
            ull* sdst = hbufF + off;
            const ull ep = ((ull)(unsigned)(t + 1)) << 32;
#pragma unroll
            for (int r = 0; r < 4; ++r) {
                ull wv = ep | (ull)hwu[r];
                *(volatile ull*)(fdst + r) = wv;   // fast: own-XCD L2
                gstll(sdst + r, wv);               // slow: MALL
            }
        }
        __syncthreads();
    }
}

// ---------------------------------------------------------------------------
// xp GEMM, F/B pair fused into one launch (unchanged).
// ---------------------------------------------------------------------------
__global__ void __launch_bounds__(256) gemm_xp2(
    const float* __restrict__ A, int M, int K, int halfgrid,
    const float* __restrict__ WvF, const float* __restrict__ baF,
    const float* __restrict__ bbF, float* __restrict__ CF,
    const float* __restrict__ WvB, const float* __restrict__ baB,
    const float* __restrict__ bbB, float* __restrict__ CB)
{
    __shared__ float At[16][66];
    __shared__ float Wt[128][66];
    const int tid = threadIdx.x;
    int bgl = blockIdx.x;
    const int rev = (bgl >= halfgrid) ? 1 : 0;
    if (rev) bgl -= halfgrid;
    const float* Wv = rev ? WvB : WvF;
    const float* ba = rev ? baB : baF;
    const float* bb = rev ? bbB : bbF;
    float* C        = rev ? CB : CF;

    const int nt = bgl & 15, mt = bgl >> 4;
    const int rp = tid >> 2, fq = tid & 3;
    const int lr0 = 2 * rp, lr1 = lr0 + 1;
    const int n0 = nt * 128 + lr0, n1 = n0 + 1;

    float acc0[4], acc1[4];
    {
        float b0 = ba[n0] + bb[n0], b1 = ba[n1] + bb[n1];
#pragma unroll
        for (int j = 0; j < 4; ++j) { acc0[j] = b0; acc1[j] = b1; }
    }

    for (int kt = 0; kt < K; kt += 64) {
        {
            int f = tid >> 4, c4 = tid & 15;
            int m = mt * 16 + f;
            float4 v = make_float4(0.f, 0.f, 0.f, 0.f);
            if (m < M) {
                int ar = rev ? (M - 1 - m) : m;
                v = ((const float4*)(A + (size_t)ar * K + kt))[c4];
            }
            At[f][c4 * 4 + 0] = v.x; At[f][c4 * 4 + 1] = v.y;
            At[f][c4 * 4 + 2] = v.z; At[f][c4 * 4 + 3] = v.w;
        }
        for (int i = tid; i < 2048; i += 256) {
            int lr = i >> 4, c4 = i & 15;
            float4 v = ((const float4*)(Wv + (size_t)(nt * 128 + lr) * K + kt))[c4];
            Wt[lr][c4 * 4 + 0] = v.x; Wt[lr][c4 * 4 + 1] = v.y;
            Wt[lr][c4 * 4 + 2] = v.z; Wt[lr][c4 * 4 + 3] = v.w;
        }
        __syncthreads();
        const float2* w0p = (const float2*)(&Wt[lr0][0]);
        const float2* w1p = (const float2*)(&Wt[lr1][0]);
#pragma unroll 8
        for (int kh = 0; kh < 32; ++kh) {
            float2 w0 = w0p[kh], w1 = w1p[kh];
#pragma unroll
            for (int j = 0; j < 4; ++j) {
                float2 av = ((const float2*)(&At[4 * fq + j][0]))[kh];
                acc0[j] += w0.x * av.x + w0.y * av.y;
                acc1[j] += w1.x * av.x + w1.y * av.y;
            }
        }
        __syncthreads();
    }
#pragma unroll
    for (int j = 0; j < 4; ++j) {
        int m = mt * 16 + 4 * fq + j;
        if (m < M) {
            C[(size_t)m * 2048 + n0] = acc0[j];
            C[(size_t)m * 2048 + n1] = acc1[j];
        }
    }
}

// ---------------------------------------------------------------------------
// Pyramidal bi-LSTM (unchanged).
// ---------------------------------------------------------------------------
__global__ void __launch_bounds__(256, 1) pyr_rec(
    const float* __restrict__ xpF, const float* __restrict__ xpB,
    const float* __restrict__ WhhF, const float* __restrict__ WhhB,
    ull* __restrict__ hp,      // [dir][2][512]
    float* __restrict__ outF, float* __restrict__ outB,
    int steps)
{
    const int tid = threadIdx.x;
    const int dir = blockIdx.x >> 6, blk = blockIdx.x & 63;
    const float* xp  = dir ? xpB : xpF;
    const float* Whh = dir ? WhhB : WhhF;
    float* outp = dir ? outB : outF;
    ull* hpd = hp + (size_t)dir * 1024;

    __shared__ __align__(16) float hcur[512];
    __shared__ float red[32][9];
    __shared__ float gv[32];

    const int lr = tid & 31, seg = tid >> 5;
    const int grow = (lr >> 3) * 512 + blk * 8 + (lr & 7);
    float4 wl4[16];
#pragma unroll
    for (int j = 0; j < 16; ++j)
        wl4[j] = *(const float4*)&Whh[(size_t)grow * 512 + 4 * seg + 32 * j];

    const int growx = (tid >> 3) * 512 + blk * 8 + (tid & 7);   // for tid<32
    float creg = 0.f;
    __syncthreads();

    for (int t = 0; t < steps; ++t) {
        float xg = 0.f;
        if (tid < 32) xg = xp[(size_t)t * 2048 + growx];   // prefetch (no h dep)
        {
            const ull* base = hpd + (size_t)(t & 1) * 512;
            ull v0 = gldll(base + tid), v1 = gldll(base + tid + 256);
            while (((int)(v0 >> 32) != t) | ((int)(v1 >> 32) != t)) {
                __builtin_amdgcn_s_sleep(1);
                v0 = gldll(base + tid);
                v1 = gldll(base + tid + 256);
            }
            hcur[tid]       = lowf(v0);
            hcur[tid + 256] = lowf(v1);
        }
        __syncthreads();

        float a = 0.f;
#pragma unroll
        for (int j = 0; j < 16; ++j) {
            float4 w = wl4[j];
            float4 h4 = *(const float4*)&hcur[4 * seg + 32 * j];
            a += w.x*h4.x + w.y*h4.y + w.z*h4.z + w.w*h4.w;
        }
        red[lr][seg] = a;
        __syncthreads();

        if (tid < 32) {
            float g = xg;
#pragma unroll
            for (int s2 = 0; s2 < 8; ++s2) g += red[tid][s2];
            gv[tid] = g;
        }
        __syncthreads();
        if (tid < 8) {
            float i_ = sigf(gv[tid]), f_ = sigf(gv[8 + tid]);
            float g_ = tanh_f(gv[16 + tid]), o_ = sigf(gv[24 + tid]);
            creg = f_ * creg + i_ * g_;
            float hn = o_ * tanh_f(creg);
            int d = blk * 8 + tid;
            gstll(&hpd[((t + 1) & 1) * 512 + d], packfe(hn, t + 1));
            int row = dir ? (steps - 1 - t) : t;
            outp[(size_t)row * 512 + d] = hn;
        }
        __syncthreads();
    }
}

__global__ void x2_assemble(const float* __restrict__ f1, const float* __restrict__ b1o,
                            float* __restrict__ x2)
{
    int j = blockIdx.x;
    for (int k = threadIdx.x; k < 2048; k += 256) {
        int q = k >> 9, r = k & 511;
        const float* src = (q & 1) ? b1o : f1;
        int row = 2 * j + (q >> 1);
        x2[(size_t)j * 2048 + k] = src[(size_t)row * 512 + r];
    }
}

// ctx assemble + publish hdec slot 0 with epoch 0
__global__ void ctx_k(const float* __restrict__ f2, const float* __restrict__ b2o,
                      float* __restrict__ ctx, ull* __restrict__ hdec_p)
{
    int j = blockIdx.x;
    for (int k = threadIdx.x; k < 1024; k += 256)
        ctx[(size_t)j * 1024 + k] = (k < 512) ? f2[(size_t)j * 512 + k]
                                              : b2o[(size_t)j * 512 + k - 512];
    if (j == 0) {
        for (int i = threadIdx.x; i < 512; i += 256)
            hdec_p[i] = packfe(f2[59 * 512 + i], 0);
    }
}

// ---------------------------------------------------------------------------
// precompute M^T: MgT[60][512] (unchanged from R11)
// ---------------------------------------------------------------------------
__global__ void __launch_bounds__(256) precomp_M(
    const float* __restrict__ comb_W,   // [512][1032]
    const float* __restrict__ ctx,      // [60][1024]
    float* __restrict__ MgT)            // [60][512]
{
    __shared__ float cw[8 * 1024];      // 32 KB: comb_W rows d0..d0+8, cols 8..1032
    const int tid = threadIdx.x, d0 = blockIdx.x * 8;
    for (int i = tid; i < 2048; i += 256) {
        int r = i >> 8, c4 = i & 255;
        float4 v = *(const float4*)&comb_W[(size_t)(d0 + r) * 1032 + 8 + 4 * c4];
        *(float4*)&cw[r * 1024 + 4 * c4] = v;
    }
    __syncthreads();
    for (int o = tid; o < 480; o += 256) {
        int dl = o / 60, j = o % 60;
        const float4* cp = (const float4*)&cw[dl * 1024];
        const float4* xp = (const float4*)(ctx + (size_t)j * 1024);
        float a = 0.f;
#pragma unroll 4
        for (int k = 0; k < 256; ++k) {
            float4 w = cp[k], x = xp[k];
            a += w.x * x.x + w.y * x.y + w.z * x.z + w.w * x.w;
        }
        MgT[(size_t)j * 512 + (d0 + dl)] = a;
    }
}

// ---------------------------------------------------------------------------
// Decoder (unchanged from R11): 64 blocks x 512 threads, register weights,
// shuffle reductions, conflict-free LDS mappings, 1-word/thread h poll.
// ---------------------------------------------------------------------------
__global__ void __launch_bounds__(512, 1) dec_k(
    const float* __restrict__ attn_W, const float* __restrict__ attn_b,
    const float* __restrict__ comb_W, const float* __restrict__ comb_b,
    const float* __restrict__ gWih, const float* __restrict__ gWhh,
    const float* __restrict__ gbih, const float* __restrict__ gbhh,
    const float* __restrict__ outW, const float* __restrict__ outb,
    const float* __restrict__ MgT,  // [60][512]
    ull* __restrict__ hdec_p,       // [2][512]
    float* __restrict__ dout)
{
    const int tid = threadIdx.x, bid = blockIdx.x;   // 64 blocks x 512 thr
    const int lane = tid & 63, wv = tid >> 6;
    const int dbase = bid * 8;

    __shared__ float M2T[68][512];                   // rows: [M(60) | Minp(8)]
    __shared__ __align__(16) float hL[520];          // h(512) + pad
    __shared__ __align__(16) float xl[512];          // o
    __shared__ __align__(16) float awx[68];          // [aw(60); inp(8)]
    __shared__ float zd[8], zh[64];
    __shared__ float ghl[24], gil[24];
    __shared__ float biasg[24], biasi[24];
    __shared__ float cbL[512];
    __shared__ float attnbL[64], outbL[8];

    // row/seg partitions
    const int rg = tid >> 4, sg = tid & 15;   // gh/gi: 24(32) rows x 16 segs
    const int rz = tid >> 3, szz = tid & 7;   // z_h: 60(64) rows x 8 segs

    // ---- weights to registers (interleaved k-mappings) ----
    float4 wo2[2];                  // logits row wv: k = 4*lane + 256*i
    float4 wg8[8], wi8[8];          // gh/gi row rg:  k = 4*sg + 64*i
    float4 wzh[16];                 // z_h row rz:    k = 4*szz + 32*i
    float4 wip[2];                  // z inp-part (row tid<60)
    {
        const float* wp = outW + (size_t)wv * 512 + 4 * lane;
        wo2[0] = *(const float4*)wp;
        wo2[1] = *(const float4*)(wp + 256);
    }
    {
        int rr = (rg < 24) ? rg : 23;
        size_t grow = (size_t)((rr >> 3) * 512 + dbase + (rr & 7)) * 512 + 4 * sg;
#pragma unroll
        for (int i = 0; i < 8; ++i) {
            wg8[i] = *(const float4*)&gWhh[grow + 64 * i];
            wi8[i] = *(const float4*)&gWih[grow + 64 * i];
        }
    }
    {
        int rr = (rz < 60) ? rz : 59;
        size_t base = (size_t)rr * 520 + 8 + 4 * szz;
#pragma unroll
        for (int i = 0; i < 16; ++i)
            wzh[i] = *(const float4*)&attn_W[base + 32 * i];
    }
    {
        int rr = (tid < 60) ? tid : 59;
        wip[0] = *(const float4*)&attn_W[(size_t)rr * 520 + 0];
        wip[1] = *(const float4*)&attn_W[(size_t)rr * 520 + 4];
    }
    if (tid < 24) {
        int g2 = (tid >> 3) * 512 + dbase + (tid & 7);
        biasg[tid] = gbhh[g2];
        biasi[tid] = gbih[g2];
    }
    cbL[tid] = comb_b[tid];
    if (tid < 64) attnbL[tid] = (tid < 60) ? attn_b[tid] : 0.f;
    if (tid < 8) outbL[tid] = outb[tid];
    // M2T rows 0..59 from MgT (coalesced), rows 60..67 = comb_W cols 0..8
    for (int i = tid; i < 7680; i += 512) {
        int j = i >> 7, c4 = i & 127;
        *(float4*)&M2T[j][4 * c4] = *(const float4*)&MgT[(size_t)j * 512 + 4 * c4];
    }
    for (int i = tid; i < 4096; i += 512) {
        int r = i >> 3, c = i & 7;
        M2T[60 + c][r] = comb_W[(size_t)r * 1032 + c];
    }
    __syncthreads();

    for (int s = 0; s < 30; ++s) {
        // ---- cross-block hop: h (slot s&1, epoch s), 1 word/thread ----
        {
            const ull* hs = hdec_p + (size_t)(s & 1) * 512;
            ull v0 = gldll(hs + tid);
            while ((int)(v0 >> 32) != s) {
                __builtin_amdgcn_s_sleep(1);
                v0 = gldll(hs + tid);
            }
            hL[tid] = lowf(v0);
        }
        __syncthreads();

        // ---- phase A: three h-matvec partials + shuffle reductions ----
        {   // logits: one wave per row, contiguous 16B-stride reads
            float a = 0.f;
            float4 h0 = *(const float4*)&hL[4 * lane];
            float4 h1 = *(const float4*)&hL[4 * lane + 256];
            a += wo2[0].x*h0.x + wo2[0].y*h0.y + wo2[0].z*h0.z + wo2[0].w*h0.w;
            a += wo2[1].x*h1.x + wo2[1].y*h1.y + wo2[1].z*h1.z + wo2[1].w*h1.w;
#pragma unroll
            for (int off = 32; off; off >>= 1) a += __shfl_xor(a, off);
            if (lane == 0) zd[wv] = a;
        }
        {   // gh: 16 segs, k = 4*sg + 64*i
            float a = 0.f;
#pragma unroll
            for (int i = 0; i < 8; ++i) {
                float4 w = wg8[i];
                float4 h4 = *(const float4*)&hL[4 * sg + 64 * i];
                a += w.x*h4.x + w.y*h4.y + w.z*h4.z + w.w*h4.w;
            }
            a += __shfl_xor(a, 1); a += __shfl_xor(a, 2);
            a += __shfl_xor(a, 4); a += __shfl_xor(a, 8);
            if (sg == 0 && rg < 24) ghl[rg] = a;
        }
        {   // z_h: 8 segs, k = 4*szz + 32*i
            float a = 0.f;
#pragma unroll
            for (int i = 0; i < 16; ++i) {
                float4 w = wzh[i];
                float4 h4 = *(const float4*)&hL[4 * szz + 32 * i];
                a += w.x*h4.x + w.y*h4.y + w.z*h4.z + w.w*h4.w;
            }
            a += __shfl_xor(a, 1); a += __shfl_xor(a, 2); a += __shfl_xor(a, 4);
            if (szz == 0 && rz < 60) zh[rz] = a;
        }
        __syncthreads();

        // ---- phase BC (wave 0): inp -> z finalize -> softmax60 ----
        if (wv == 0) {
            if (lane < 8) {
                float v;
                if (s > 0) {
                    float a = zd[lane] + outbL[lane];
                    float m = a;
                    m = fmaxf(m, __shfl_xor(m, 1));
                    m = fmaxf(m, __shfl_xor(m, 2));
                    m = fmaxf(m, __shfl_xor(m, 4));
                    float e = __expf(a - m);
                    float ss2 = e;
                    ss2 += __shfl_xor(ss2, 1);
                    ss2 += __shfl_xor(ss2, 2);
                    ss2 += __shfl_xor(ss2, 4);
                    v = a - m - __logf(ss2);
                    if (bid == 0) dout[(s - 1) * 8 + lane] = v;
                } else {
                    v = (lane == 7) ? 1.f : 0.f;
                }
                awx[60 + lane] = v;
            }
            // z = zh + b + attn_W[:,0:8] @ inp  (same-wave LDS ordering)
            float z = -1e30f;
            if (lane < 60) {
                z = zh[lane] + attnbL[lane]
                  + wip[0].x * awx[60] + wip[0].y * awx[61]
                  + wip[0].z * awx[62] + wip[0].w * awx[63]
                  + wip[1].x * awx[64] + wip[1].y * awx[65]
                  + wip[1].z * awx[66] + wip[1].w * awx[67];
            }
            float m = z;
#pragma unroll
            for (int off = 32; off; off >>= 1) m = fmaxf(m, __shfl_xor(m, off));
            float e = (lane < 60) ? __expf(z - m) : 0.f;
            float ss2 = e;
#pragma unroll
            for (int off = 32; off; off >>= 1) ss2 += __shfl_xor(ss2, off);
            if (lane < 60) awx[lane] = e / ss2;
        }
        __syncthreads();

        // ---- phase E: o = relu(M2T^T @ [aw; inp] + comb_b), 1 dim/thread ----
        {
            float a = cbL[tid];
#pragma unroll 4
            for (int k = 0; k < 68; ++k)
                a += M2T[k][tid] * awx[k];
            xl[tid] = fmaxf(a, 0.f);
        }
        __syncthreads();

        // ---- phase F: gi = gWih @ o, k = 4*sg + 64*i ----
        {
            float a = 0.f;
#pragma unroll
            for (int i = 0; i < 8; ++i) {
                float4 w = wi8[i];
                float4 o4 = *(const float4*)&xl[4 * sg + 64 * i];
                a += w.x*o4.x + w.y*o4.y + w.z*o4.z + w.w*o4.w;
            }
            a += __shfl_xor(a, 1); a += __shfl_xor(a, 2);
            a += __shfl_xor(a, 4); a += __shfl_xor(a, 8);
            if (sg == 0 && rg < 24) gil[rg] = a;
        }
        __syncthreads();

        // ---- phase G: GRU combine + publish (8 threads) ----
        if (tid < 8) {
            float gh0 = biasg[tid] + ghl[tid];
            float gh1 = biasg[8 + tid] + ghl[8 + tid];
            float gh2 = biasg[16 + tid] + ghl[16 + tid];
            float gi0 = biasi[tid] + gil[tid];
            float gi1 = biasi[8 + tid] + gil[8 + tid];
            float gi2 = biasi[16 + tid] + gil[16 + tid];
            float r_ = sigf(gi0 + gh0);
            float z_ = sigf(gi1 + gh1);
            float n_ = tanh_f(gi2 + r_ * gh2);
            float hnew = (1.f - z_) * n_ + z_ * hL[dbase + tid];
            gstll(&hdec_p[(size_t)((s + 1) & 1) * 512 + dbase + tid], packfe(hnew, s + 1));
        }
        __syncthreads();   // protect hL/awx/xl before next-step overwrite
    }

    // epilogue: logits for s=29 (block 0 only)
    if (bid == 0) {
        {
            const ull* hs = hdec_p + (size_t)(30 & 1) * 512;
            ull v0 = gldll(hs + tid);
            while ((int)(v0 >> 32) != 30) {
                __builtin_amdgcn_s_sleep(1);
                v0 = gldll(hs + tid);
            }
            hL[tid] = lowf(v0);
        }
        __syncthreads();
        {
            float a = 0.f;
            float4 h0 = *(const float4*)&hL[4 * lane];
            float4 h1 = *(const float4*)&hL[4 * lane + 256];
            a += wo2[0].x*h0.x + wo2[0].y*h0.y + wo2[0].z*h0.z + wo2[0].w*h0.w;
            a += wo2[1].x*h1.x + wo2[1].y*h1.y + wo2[1].z*h1.z + wo2[1].w*h1.w;
#pragma unroll
            for (int off = 32; off; off >>= 1) a += __shfl_xor(a, off);
            if (lane == 0) zd[wv] = a;
        }
        __syncthreads();
        if (tid < 8) {
            float a = zd[tid] + outbL[tid];
            float m = a;
            m = fmaxf(m, __shfl_xor(m, 1));
            m = fmaxf(m, __shfl_xor(m, 2));
            m = fmaxf(m, __shfl_xor(m, 4));
            float e = __expf(a - m);
            float ss2 = e;
            ss2 += __shfl_xor(ss2, 1);
            ss2 += __shfl_xor(ss2, 2);
            ss2 += __shfl_xor(ss2, 4);
            dout[29 * 8 + tid] = a - m - __logf(ss2);
        }
    }
}

// ---------------------------------------------------------------------------
extern "C" void kernel_launch(void* const* d_in, const int* in_sizes, int n_in,
                              void* d_out, int out_size, void* d_ws, size_t ws_size,
                              hipStream_t stream) {
    (void)in_sizes; (void)n_in; (void)out_size; (void)ws_size;
    const float* data    = (const float*)d_in[0];
    const float* enc_Wih = (const float*)d_in[1];
    const float* enc_Whh = (const float*)d_in[2];
    const float* enc_bih = (const float*)d_in[3];
    const float* enc_bhh = (const float*)d_in[4];
    const float* p1f_Wih = (const float*)d_in[5];
    const float* p1f_Whh = (const float*)d_in[6];
    const float* p1f_bih = (const float*)d_in[7];
    const float* p1f_bhh = (const float*)d_in[8];
    const float* p1b_Wih = (const float*)d_in[9];
    const float* p1b_Whh = (const float*)d_in[10];
    const float* p1b_bih = (const float*)d_in[11];
    const float* p1b_bhh = (const float*)d_in[12];
    const float* p2f_Wih = (const float*)d_in[13];
    const float* p2f_Whh = (const float*)d_in[14];
    const float* p2f_bih = (const float*)d_in[15];
    const float* p2f_bhh = (const float*)d_in[16];
    const float* p2b_Wih = (const float*)d_in[17];
    const float* p2b_Whh = (const float*)d_in[18];
    const float* p2b_bih = (const float*)d_in[19];
    const float* p2b_bhh = (const float*)d_in[20];
    const float* attn_W  = (const float*)d_in[21];
    const float* attn_b  = (const float*)d_in[22];
    const float* comb_W  = (const float*)d_in[23];
    const float* comb_b  = (const float*)d_in[24];
    const float* gru_Wih = (const float*)d_in[25];
    const float* gru_Whh = (const float*)d_in[26];
    const float* gru_bih = (const float*)d_in[27];
    const float* gru_bhh = (const float*)d_in[28];
    const float* out_W   = (const float*)d_in[29];
    const float* out_b   = (const float*)d_in[30];

    float* ws = (float*)d_ws;
    // zeroed region [0 .. 501760)
    ull* fastF   = (ull*)ws;                 // 245760 floats = [2][15][4096] ull
    ull* hbufF   = (ull*)(ws + 245760);      // 245760 floats = [2][15][4096] ull
    ull* hp1     = (ull*)(ws + 491520);      // 4096 floats = [2][2][512] ull
    ull* hp2     = (ull*)(ws + 495616);      // 4096 floats
    ull* hdec_p  = (ull*)(ws + 499712);      // 2048 floats -> end 501760
    // non-zeroed scratch
    float* henc  = ws + 501760;              // 122880
    float* xp1f  = ws + 624640;              // 245760
    float* xp1b  = ws + 870400;              // 245760
    float* f1    = ws + 1116160;             // 61440
    float* b1o   = ws + 1177600;             // 61440
    float* x2    = ws + 1239040;             // 122880
    float* xp2f  = ws + 1361920;             // 122880
    float* xp2b  = ws + 1484800;             // 122880
    float* f2    = ws + 1607680;             // 30720
    float* b2o   = ws + 1638400;             // 30720
    float* ctxb  = ws + 1669120;             // 61440
    float* MgT   = ws + 1730560;             // 30720 -> end 1761280

    init_k<<<256, 256, 0, stream>>>(ws);

    enc_all<<<256, 256, 0, stream>>>(data, enc_Wih, enc_Whh, enc_bih, enc_bhh,
                                     fastF, hbufF, henc);
    gemm_xp2<<<256, 256, 0, stream>>>(henc, 120, 1024, 128,
                                      p1f_Wih, p1f_bih, p1f_bhh, xp1f,
                                      p1b_Wih, p1b_bih, p1b_bhh, xp1b);
    pyr_rec<<<128, 256, 0, stream>>>(xp1f, xp1b, p1f_Whh, p1b_Whh, hp1, f1, b1o, 120);
    x2_assemble<<<60, 256, 0, stream>>>(f1, b1o, x2);
    gemm_xp2<<<128, 256, 0, stream>>>(x2, 60, 2048, 64,
                                      p2f_Wih, p2f_bih, p2f_bhh, xp2f,
                                      p2b_Wih, p2b_bih, p2b_bhh, xp2b);
    pyr_rec<<<128, 256, 0, stream>>>(xp2f, xp2b, p2f_Whh, p2b_Whh, hp2, f2, b2o, 60);
    ctx_k<<<60, 256, 0, stream>>>(f2, b2o, ctxb, hdec_p);
    precomp_M<<<64, 256, 0, stream>>>(comb_W, ctxb, MgT);
    dec_k<<<64, 512, 0, stream>>>(attn_W, attn_b, comb_W, comb_b,
                                  gru_Wih, gru_Whh, gru_bih, gru_bhh,
                                  out_W, out_b, MgT, hdec_p,
                                  (float*)d_out);
}

// Round 9
// 1438.739 us; speedup vs baseline: 1.0026x; 1.0026x over previous
//
#include <hip/hip_runtime.h>
#include <math.h>

// Model dims: H=512 D=128 L=8 T=64 W=240 CTX=60 NSTEPS=30

typedef __attribute__((ext_vector_type(8))) short short8;
typedef __attribute__((ext_vector_type(4))) float floatx4;
typedef unsigned long long ull;

__device__ __forceinline__ float sigf(float x) { return 1.f / (1.f + __expf(-x)); }
__device__ __forceinline__ float tanh_f(float x) {
    float e = __expf(2.f * x);
    return 1.f - 2.f / (e + 1.f);
}
__device__ __forceinline__ unsigned short f2b(float x) {   // fp32 -> bf16 RNE
    unsigned u = __float_as_uint(x);
    unsigned r = (u + 0x7FFFu + ((u >> 16) & 1u)) >> 16;
    return (unsigned short)r;
}

// RELAXED agent-scope atomics only (acquire/release emit buffer_inv/wbl2 on
// gfx950 and trash the XCD L2). Cross-block payloads are {epoch|data} ull
// words polled directly, batch-polled.
// R13 (post-mortem of R12's -81% regression): the bid&7 block->XCD heuristic
// was WRONG (FETCH dropped but time rose: fast-path loads hit the consumer's
// L2 with STALE lines -> producer on a different XCD). This round groups by
// the REAL XCD id: s_getreg(HW_REG_XCC_ID=20, measured learn_hip m09) +
// per-XCD slot claim + arrival barrier + prefix-sum -> guaranteed bijection
// onto work items for ANY id distribution (no deadlock), XCD-pure groups
// when the scheduler balances. The fast (volatile->own-L2) path is
// CREDIT-GATED: 3 consecutive steps without a fast match disable it for the
// rest of the kernel, bounding the R12 failure mode to ~3 steps. Slow path
// (agent/MALL) is unchanged R9-R11 and always polled as the escape.
__device__ __forceinline__ float gld(const float* p) {
    return __hip_atomic_load(p, __ATOMIC_RELAXED, __HIP_MEMORY_SCOPE_AGENT);
}
__device__ __forceinline__ void gst(float* p, float v) {
    __hip_atomic_store(p, v, __ATOMIC_RELAXED, __HIP_MEMORY_SCOPE_AGENT);
}
__device__ __forceinline__ ull gldll(const ull* p) {
    return __hip_atomic_load(p, __ATOMIC_RELAXED, __HIP_MEMORY_SCOPE_AGENT);
}
__device__ __forceinline__ void gstll(ull* p, ull v) {
    __hip_atomic_store(p, v, __ATOMIC_RELAXED, __HIP_MEMORY_SCOPE_AGENT);
}
__device__ __forceinline__ int gldi(const int* p) {
    return __hip_atomic_load(p, __ATOMIC_RELAXED, __HIP_MEMORY_SCOPE_AGENT);
}
__device__ __forceinline__ ull packfe(float d, int ep) {
    return ((ull)(unsigned)ep << 32) | (ull)__float_as_uint(d);
}
__device__ __forceinline__ float lowf(ull v) { return __uint_as_float((unsigned)v); }

// HW_REG_XCC_ID = 20 (gfx940+), bits [3:0]: imm = (size-1)<<11 | off<<6 | id
#define XCC_GETREG_IMM ((3 << 11) | (0 << 6) | 20)

// ---------------------------------------------------------------------------
// init: zero [fastF(245760f) | hbufF(245760f) | hp1 | hp2 | hdec | claim(16)]
//        = 501776 f
// ---------------------------------------------------------------------------
__global__ void init_k(float* __restrict__ ws) {
    for (int i = blockIdx.x * blockDim.x + threadIdx.x; i < 501776; i += gridDim.x * blockDim.x)
        ws[i] = 0.f;
}

// ---------------------------------------------------------------------------
// Encoder, ONE persistent launch, 64 steps, bf16 MFMA.
// R13: claim-based XCD-pure groups + credit-gated dual-path h exchange.
// ---------------------------------------------------------------------------
__global__ void __launch_bounds__(256, 1) enc_all(
    const float* __restrict__ data,
    const float* __restrict__ Wih, const float* __restrict__ Whh,
    const float* __restrict__ bih, const float* __restrict__ bhh,
    ull* __restrict__ fastF,        // [2][15][4096] {epoch|bf16x2}, L2 fast path
    ull* __restrict__ hbufF,        // [2][15][4096] {epoch|bf16x2}, MALL path
    float* __restrict__ henc,       // [240][512] fp32 final h
    int* __restrict__ claim)        // [0..7]=per-XCD cnt, [8]=arrivals
{
    __shared__ short act2[20 * 64 * 8];
    __shared__ float gw[4][640];
    __shared__ float cs[512];
    __shared__ short hw[4][16][8];
    __shared__ float biasL[4][4][8];
    __shared__ int sWork;

    const int tid = threadIdx.x;

    // ---- XCD-aware work claim (bijective for ANY id distribution) ----
    if (tid == 0) {
        unsigned xcd = __builtin_amdgcn_s_getreg(XCC_GETREG_IMM) & 7u;
        int slot = __hip_atomic_fetch_add(&claim[xcd], 1, __ATOMIC_RELAXED,
                                          __HIP_MEMORY_SCOPE_AGENT);
        // arrival increment data-depends on slot -> orders after the claim RMW
        __hip_atomic_fetch_add(&claim[8], 1 + (slot >> 20), __ATOMIC_RELAXED,
                               __HIP_MEMORY_SCOPE_AGENT);
        while (gldi(&claim[8]) < 256) __builtin_amdgcn_s_sleep(1);
        int pre = 0;
        for (int x = 0; x < 8; ++x) {
            int c = gldi(&claim[x]);
            if (x < (int)xcd) pre += c;
        }
        sWork = pre + slot;
    }
    __syncthreads();
    const int work = sWork;
    if (work >= 240) return;            // 16 spare blocks idle
    const int fg = work >> 4, ds = work & 15;

    const int w = tid >> 6, lane = tid & 63;
    const int n = lane & 15, q = lane >> 4;

    short8 bfrag[2][20];
#pragma unroll
    for (int nt = 0; nt < 2; ++nt) {
        int rr = nt * 16 + n;
        int g = rr >> 3, dp = rr & 7;
        int grow = g * 512 + ds * 32 + w * 8 + dp;
#pragma unroll
        for (int kt = 0; kt < 20; ++kt) {
            int k0 = kt * 32 + q * 8;
            const float* src = (k0 < 512) ? (Whh + (size_t)grow * 512 + k0)
                                          : (Wih + (size_t)grow * 128 + (k0 - 512));
            float4 lo = *(const float4*)src;
            float4 hi = *(const float4*)(src + 4);
            short8 bf;
            bf[0] = (short)f2b(lo.x); bf[1] = (short)f2b(lo.y);
            bf[2] = (short)f2b(lo.z); bf[3] = (short)f2b(lo.w);
            bf[4] = (short)f2b(hi.x); bf[5] = (short)f2b(hi.y);
            bf[6] = (short)f2b(hi.z); bf[7] = (short)f2b(hi.w);
            bfrag[nt][kt] = bf;
        }
    }
    if (tid < 128) {
        int w2 = tid >> 5, rr = tid & 31;
        int g = rr >> 3, dp = rr & 7;
        int grow = g * 512 + ds * 32 + w2 * 8 + dp;
        biasL[w2][g][dp] = bih[grow] + bhh[grow];
    }
    for (int i = tid; i < 512; i += 256) cs[i] = 0.f;
    __syncthreads();

    unsigned* a2u = (unsigned*)act2;
    int fastOK = 1, fcredit = 3;

    for (int t = 0; t < 64; ++t) {
        // x prefetch FIRST: global loads issue, latency hides under the h poll
        const int kt2 = tid >> 6, l2 = tid & 63, f2v = l2 & 15, q2 = l2 >> 4;
        const float* xs = data + ((size_t)t * 240 + fg * 16 + f2v) * 128 + kt2 * 32 + q2 * 8;
        float4 lo = *(const float4*)xs;
        float4 hi = *(const float4*)(xs + 4);

        // h gather: credit-gated dual-path batch poll of 16 words
        {
            const size_t goff = (size_t)((t & 1) * 15 + fg) * 4096;
            const ull* fsrc = fastF + goff;
            const ull* ssrc = hbufF + goff;
            ull v[16];
            bool gotFast = false;
            for (;;) {
                if (fastOK) {            // fast: own-XCD L2 (volatile bypasses L1)
                    bool ok = true;
#pragma unroll
                    for (int k2 = 0; k2 < 16; ++k2) {
                        v[k2] = *(volatile const ull*)(fsrc + tid + 256 * k2);
                        ok &= ((int)(v[k2] >> 32) == t);
                    }
                    if (ok) { gotFast = true; break; }
                }
                {                        // slow: MALL (agent scope), always correct
                    bool ok = true;
#pragma unroll
                    for (int k2 = 0; k2 < 16; ++k2) {
                        v[k2] = gldll(ssrc + tid + 256 * k2);
                        ok &= ((int)(v[k2] >> 32) == t);
                    }
                    if (ok) break;
                }
                __builtin_amdgcn_s_sleep(1);
            }
            if (fastOK && !gotFast) {    // fast path not delivering -> disable
                if (--fcredit <= 0) fastOK = 0;
            }
#pragma unroll
            for (int k2 = 0; k2 < 16; ++k2)
                a2u[tid + 256 * k2] = (unsigned)v[k2];
        }
        {
            short8 xp;
            xp[0] = (short)f2b(lo.x); xp[1] = (short)f2b(lo.y);
            xp[2] = (short)f2b(lo.z); xp[3] = (short)f2b(lo.w);
            xp[4] = (short)f2b(hi.x); xp[5] = (short)f2b(hi.y);
            xp[6] = (short)f2b(hi.z); xp[7] = (short)f2b(hi.w);
            *(short8*)&act2[((16 + kt2) * 64 + l2) * 8] = xp;
        }
        __syncthreads();

        floatx4 acc0 = {0.f, 0.f, 0.f, 0.f};
        floatx4 acc1 = {0.f, 0.f, 0.f, 0.f};
#pragma unroll
        for (int kt = 0; kt < 20; ++kt) {
            short8 a = *(short8*)&act2[(kt * 64 + lane) * 8];
            acc0 = __builtin_amdgcn_mfma_f32_16x16x32_bf16(a, bfrag[0][kt], acc0, 0, 0, 0);
            acc1 = __builtin_amdgcn_mfma_f32_16x16x32_bf16(a, bfrag[1][kt], acc1, 0, 0, 0);
        }
        *(floatx4*)&gw[w][(0 * 16 + n) * 20 + 4 * q] = acc0;
        *(floatx4*)&gw[w][(1 * 16 + n) * 20 + 4 * q] = acc1;

        int nb = (t + 1) & 1;
#pragma unroll
        for (int it = 0; it < 2; ++it) {
            int f = lane & 15, dp = q + 4 * it;
            float gi = gw[w][(0 * 8 + dp) * 20 + f] + biasL[w][0][dp];
            float gf = gw[w][(1 * 8 + dp) * 20 + f] + biasL[w][1][dp];
            float gg = gw[w][(2 * 8 + dp) * 20 + f] + biasL[w][2][dp];
            float go = gw[w][(3 * 8 + dp) * 20 + f] + biasL[w][3][dp];
            int ci = f * 32 + w * 8 + dp;
            float cc = cs[ci];
            float cn = sigf(gf) * cc + sigf(gi) * tanh_f(gg);
            float hn = sigf(go) * tanh_f(cn);
            cs[ci] = cn;
            hw[w][f][dp] = (short)f2b(hn);
            if (t == 63)
                gst(&henc[(size_t)(fg * 16 + f) * 512 + ds * 32 + w * 8 + dp], hn);
        }
        if (lane < 16) {
            const unsigned* hwu = (const unsigned*)&hw[w][lane][0];
            size_t off = (size_t)(nb * 15 + fg) * 4096 + (ds * 64 + w * 16 + lane) * 4;
            ull* fdst = fastF + off;
            ull* sdst = hbufF + off;
            const ull ep = ((ull)(unsigned)(t + 1)) << 32;
#pragma unroll
            for (int r = 0; r < 4; ++r) {
                ull wv = ep | (ull)hwu[r];
                *(volatile ull*)(fdst + r) = wv;   // fast: own-XCD L2
                gstll(sdst + r, wv);               // slow: MALL
            }
        }
        __syncthreads();
    }
}

// ---------------------------------------------------------------------------
// xp GEMM, F/B pair fused into one launch (unchanged).
// ---------------------------------------------------------------------------
__global__ void __launch_bounds__(256) gemm_xp2(
    const float* __restrict__ A, int M, int K, int halfgrid,
    const float* __restrict__ WvF, const float* __restrict__ baF,
    const float* __restrict__ bbF, float* __restrict__ CF,
    const float* __restrict__ WvB, const float* __restrict__ baB,
    const float* __restrict__ bbB, float* __restrict__ CB)
{
    __shared__ float At[16][66];
    __shared__ float Wt[128][66];
    const int tid = threadIdx.x;
    int bgl = blockIdx.x;
    const int rev = (bgl >= halfgrid) ? 1 : 0;
    if (rev) bgl -= halfgrid;
    const float* Wv = rev ? WvB : WvF;
    const float* ba = rev ? baB : baF;
    const float* bb = rev ? bbB : bbF;
    float* C        = rev ? CB : CF;

    const int nt = bgl & 15, mt = bgl >> 4;
    const int rp = tid >> 2, fq = tid & 3;
    const int lr0 = 2 * rp, lr1 = lr0 + 1;
    const int n0 = nt * 128 + lr0, n1 = n0 + 1;

    float acc0[4], acc1[4];
    {
        float b0 = ba[n0] + bb[n0], b1 = ba[n1] + bb[n1];
#pragma unroll
        for (int j = 0; j < 4; ++j) { acc0[j] = b0; acc1[j] = b1; }
    }

    for (int kt = 0; kt < K; kt += 64) {
        {
            int f = tid >> 4, c4 = tid & 15;
            int m = mt * 16 + f;
            float4 v = make_float4(0.f, 0.f, 0.f, 0.f);
            if (m < M) {
                int ar = rev ? (M - 1 - m) : m;
                v = ((const float4*)(A + (size_t)ar * K + kt))[c4];
            }
            At[f][c4 * 4 + 0] = v.x; At[f][c4 * 4 + 1] = v.y;
            At[f][c4 * 4 + 2] = v.z; At[f][c4 * 4 + 3] = v.w;
        }
        for (int i = tid; i < 2048; i += 256) {
            int lr = i >> 4, c4 = i & 15;
            float4 v = ((const float4*)(Wv + (size_t)(nt * 128 + lr) * K + kt))[c4];
            Wt[lr][c4 * 4 + 0] = v.x; Wt[lr][c4 * 4 + 1] = v.y;
            Wt[lr][c4 * 4 + 2] = v.z; Wt[lr][c4 * 4 + 3] = v.w;
        }
        __syncthreads();
        const float2* w0p = (const float2*)(&Wt[lr0][0]);
        const float2* w1p = (const float2*)(&Wt[lr1][0]);
#pragma unroll 8
        for (int kh = 0; kh < 32; ++kh) {
            float2 w0 = w0p[kh], w1 = w1p[kh];
#pragma unroll
            for (int j = 0; j < 4; ++j) {
                float2 av = ((const float2*)(&At[4 * fq + j][0]))[kh];
                acc0[j] += w0.x * av.x + w0.y * av.y;
                acc1[j] += w1.x * av.x + w1.y * av.y;
            }
        }
        __syncthreads();
    }
#pragma unroll
    for (int j = 0; j < 4; ++j) {
        int m = mt * 16 + 4 * fq + j;
        if (m < M) {
            C[(size_t)m * 2048 + n0] = acc0[j];
            C[(size_t)m * 2048 + n1] = acc1[j];
        }
    }
}

// ---------------------------------------------------------------------------
// Pyramidal bi-LSTM (unchanged).
// ---------------------------------------------------------------------------
__global__ void __launch_bounds__(256, 1) pyr_rec(
    const float* __restrict__ xpF, const float* __restrict__ xpB,
    const float* __restrict__ WhhF, const float* __restrict__ WhhB,
    ull* __restrict__ hp,      // [dir][2][512]
    float* __restrict__ outF, float* __restrict__ outB,
    int steps)
{
    const int tid = threadIdx.x;
    const int dir = blockIdx.x >> 6, blk = blockIdx.x & 63;
    const float* xp  = dir ? xpB : xpF;
    const float* Whh = dir ? WhhB : WhhF;
    float* outp = dir ? outB : outF;
    ull* hpd = hp + (size_t)dir * 1024;

    __shared__ __align__(16) float hcur[512];
    __shared__ float red[32][9];
    __shared__ float gv[32];

    const int lr = tid & 31, seg = tid >> 5;
    const int grow = (lr >> 3) * 512 + blk * 8 + (lr & 7);
    float4 wl4[16];
#pragma unroll
    for (int j = 0; j < 16; ++j)
        wl4[j] = *(const float4*)&Whh[(size_t)grow * 512 + 4 * seg + 32 * j];

    const int growx = (tid >> 3) * 512 + blk * 8 + (tid & 7);   // for tid<32
    float creg = 0.f;
    __syncthreads();

    for (int t = 0; t < steps; ++t) {
        float xg = 0.f;
        if (tid < 32) xg = xp[(size_t)t * 2048 + growx];   // prefetch (no h dep)
        {
            const ull* base = hpd + (size_t)(t & 1) * 512;
            ull v0 = gldll(base + tid), v1 = gldll(base + tid + 256);
            while (((int)(v0 >> 32) != t) | ((int)(v1 >> 32) != t)) {
                __builtin_amdgcn_s_sleep(1);
                v0 = gldll(base + tid);
                v1 = gldll(base + tid + 256);
            }
            hcur[tid]       = lowf(v0);
            hcur[tid + 256] = lowf(v1);
        }
        __syncthreads();

        float a = 0.f;
#pragma unroll
        for (int j = 0; j < 16; ++j) {
            float4 w = wl4[j];
            float4 h4 = *(const float4*)&hcur[4 * seg + 32 * j];
            a += w.x*h4.x + w.y*h4.y + w.z*h4.z + w.w*h4.w;
        }
        red[lr][seg] = a;
        __syncthreads();

        if (tid < 32) {
            float g = xg;
#pragma unroll
            for (int s2 = 0; s2 < 8; ++s2) g += red[tid][s2];
            gv[tid] = g;
        }
        __syncthreads();
        if (tid < 8) {
            float i_ = sigf(gv[tid]), f_ = sigf(gv[8 + tid]);
            float g_ = tanh_f(gv[16 + tid]), o_ = sigf(gv[24 + tid]);
            creg = f_ * creg + i_ * g_;
            float hn = o_ * tanh_f(creg);
            int d = blk * 8 + tid;
            gstll(&hpd[((t + 1) & 1) * 512 + d], packfe(hn, t + 1));
            int row = dir ? (steps - 1 - t) : t;
            outp[(size_t)row * 512 + d] = hn;
        }
        __syncthreads();
    }
}

__global__ void x2_assemble(const float* __restrict__ f1, const float* __restrict__ b1o,
                            float* __restrict__ x2)
{
    int j = blockIdx.x;
    for (int k = threadIdx.x; k < 2048; k += 256) {
        int q = k >> 9, r = k & 511;
        const float* src = (q & 1) ? b1o : f1;
        int row = 2 * j + (q >> 1);
        x2[(size_t)j * 2048 + k] = src[(size_t)row * 512 + r];
    }
}

// ctx assemble + publish hdec slot 0 with epoch 0
__global__ void ctx_k(const float* __restrict__ f2, const float* __restrict__ b2o,
                      float* __restrict__ ctx, ull* __restrict__ hdec_p)
{
    int j = blockIdx.x;
    for (int k = threadIdx.x; k < 1024; k += 256)
        ctx[(size_t)j * 1024 + k] = (k < 512) ? f2[(size_t)j * 512 + k]
                                              : b2o[(size_t)j * 512 + k - 512];
    if (j == 0) {
        for (int i = threadIdx.x; i < 512; i += 256)
            hdec_p[i] = packfe(f2[59 * 512 + i], 0);
    }
}

// ---------------------------------------------------------------------------
// precompute M^T: MgT[60][512] (unchanged from R11)
// ---------------------------------------------------------------------------
__global__ void __launch_bounds__(256) precomp_M(
    const float* __restrict__ comb_W,   // [512][1032]
    const float* __restrict__ ctx,      // [60][1024]
    float* __restrict__ MgT)            // [60][512]
{
    __shared__ float cw[8 * 1024];      // 32 KB: comb_W rows d0..d0+8, cols 8..1032
    const int tid = threadIdx.x, d0 = blockIdx.x * 8;
    for (int i = tid; i < 2048; i += 256) {
        int r = i >> 8, c4 = i & 255;
        float4 v = *(const float4*)&comb_W[(size_t)(d0 + r) * 1032 + 8 + 4 * c4];
        *(float4*)&cw[r * 1024 + 4 * c4] = v;
    }
    __syncthreads();
    for (int o = tid; o < 480; o += 256) {
        int dl = o / 60, j = o % 60;
        const float4* cp = (const float4*)&cw[dl * 1024];
        const float4* xp = (const float4*)(ctx + (size_t)j * 1024);
        float a = 0.f;
#pragma unroll 4
        for (int k = 0; k < 256; ++k) {
            float4 w = cp[k], x = xp[k];
            a += w.x * x.x + w.y * x.y + w.z * x.z + w.w * x.w;
        }
        MgT[(size_t)j * 512 + (d0 + dl)] = a;
    }
}

// ---------------------------------------------------------------------------
// Decoder (unchanged from R11): 64 blocks x 512 threads, register weights,
// shuffle reductions, conflict-free LDS mappings, 1-word/thread h poll.
// ---------------------------------------------------------------------------
__global__ void __launch_bounds__(512, 1) dec_k(
    const float* __restrict__ attn_W, const float* __restrict__ attn_b,
    const float* __restrict__ comb_W, const float* __restrict__ comb_b,
    const float* __restrict__ gWih, const float* __restrict__ gWhh,
    const float* __restrict__ gbih, const float* __restrict__ gbhh,
    const float* __restrict__ outW, const float* __restrict__ outb,
    const float* __restrict__ MgT,  // [60][512]
    ull* __restrict__ hdec_p,       // [2][512]
    float* __restrict__ dout)
{
    const int tid = threadIdx.x, bid = blockIdx.x;   // 64 blocks x 512 thr
    const int lane = tid & 63, wv = tid >> 6;
    const int dbase = bid * 8;

    __shared__ float M2T[68][512];                   // rows: [M(60) | Minp(8)]
    __shared__ __align__(16) float hL[520];          // h(512) + pad
    __shared__ __align__(16) float xl[512];          // o
    __shared__ __align__(16) float awx[68];          // [aw(60); inp(8)]
    __shared__ float zd[8], zh[64];
    __shared__ float ghl[24], gil[24];
    __shared__ float biasg[24], biasi[24];
    __shared__ float cbL[512];
    __shared__ float attnbL[64], outbL[8];

    // row/seg partitions
    const int rg = tid >> 4, sg = tid & 15;   // gh/gi: 24(32) rows x 16 segs
    const int rz = tid >> 3, szz = tid & 7;   // z_h: 60(64) rows x 8 segs

    // ---- weights to registers (interleaved k-mappings) ----
    float4 wo2[2];                  // logits row wv: k = 4*lane + 256*i
    float4 wg8[8], wi8[8];          // gh/gi row rg:  k = 4*sg + 64*i
    float4 wzh[16];                 // z_h row rz:    k = 4*szz + 32*i
    float4 wip[2];                  // z inp-part (row tid<60)
    {
        const float* wp = outW + (size_t)wv * 512 + 4 * lane;
        wo2[0] = *(const float4*)wp;
        wo2[1] = *(const float4*)(wp + 256);
    }
    {
        int rr = (rg < 24) ? rg : 23;
        size_t grow = (size_t)((rr >> 3) * 512 + dbase + (rr & 7)) * 512 + 4 * sg;
#pragma unroll
        for (int i = 0; i < 8; ++i) {
            wg8[i] = *(const float4*)&gWhh[grow + 64 * i];
            wi8[i] = *(const float4*)&gWih[grow + 64 * i];
        }
    }
    {
        int rr = (rz < 60) ? rz : 59;
        size_t base = (size_t)rr * 520 + 8 + 4 * szz;
#pragma unroll
        for (int i = 0; i < 16; ++i)
            wzh[i] = *(const float4*)&attn_W[base + 32 * i];
    }
    {
        int rr = (tid < 60) ? tid : 59;
        wip[0] = *(const float4*)&attn_W[(size_t)rr * 520 + 0];
        wip[1] = *(const float4*)&attn_W[(size_t)rr * 520 + 4];
    }
    if (tid < 24) {
        int g2 = (tid >> 3) * 512 + dbase + (tid & 7);
        biasg[tid] = gbhh[g2];
        biasi[tid] = gbih[g2];
    }
    cbL[tid] = comb_b[tid];
    if (tid < 64) attnbL[tid] = (tid < 60) ? attn_b[tid] : 0.f;
    if (tid < 8) outbL[tid] = outb[tid];
    // M2T rows 0..59 from MgT (coalesced), rows 60..67 = comb_W cols 0..8
    for (int i = tid; i < 7680; i += 512) {
        int j = i >> 7, c4 = i & 127;
        *(float4*)&M2T[j][4 * c4] = *(const float4*)&MgT[(size_t)j * 512 + 4 * c4];
    }
    for (int i = tid; i < 4096; i += 512) {
        int r = i >> 3, c = i & 7;
        M2T[60 + c][r] = comb_W[(size_t)r * 1032 + c];
    }
    __syncthreads();

    for (int s = 0; s < 30; ++s) {
        // ---- cross-block hop: h (slot s&1, epoch s), 1 word/thread ----
        {
            const ull* hs = hdec_p + (size_t)(s & 1) * 512;
            ull v0 = gldll(hs + tid);
            while ((int)(v0 >> 32) != s) {
                __builtin_amdgcn_s_sleep(1);
                v0 = gldll(hs + tid);
            }
            hL[tid] = lowf(v0);
        }
        __syncthreads();

        // ---- phase A: three h-matvec partials + shuffle reductions ----
        {   // logits: one wave per row, contiguous 16B-stride reads
            float a = 0.f;
            float4 h0 = *(const float4*)&hL[4 * lane];
            float4 h1 = *(const float4*)&hL[4 * lane + 256];
            a += wo2[0].x*h0.x + wo2[0].y*h0.y + wo2[0].z*h0.z + wo2[0].w*h0.w;
            a += wo2[1].x*h1.x + wo2[1].y*h1.y + wo2[1].z*h1.z + wo2[1].w*h1.w;
#pragma unroll
            for (int off = 32; off; off >>= 1) a += __shfl_xor(a, off);
            if (lane == 0) zd[wv] = a;
        }
        {   // gh: 16 segs, k = 4*sg + 64*i
            float a = 0.f;
#pragma unroll
            for (int i = 0; i < 8; ++i) {
                float4 w = wg8[i];
                float4 h4 = *(const float4*)&hL[4 * sg + 64 * i];
                a += w.x*h4.x + w.y*h4.y + w.z*h4.z + w.w*h4.w;
            }
            a += __shfl_xor(a, 1); a += __shfl_xor(a, 2);
            a += __shfl_xor(a, 4); a += __shfl_xor(a, 8);
            if (sg == 0 && rg < 24) ghl[rg] = a;
        }
        {   // z_h: 8 segs, k = 4*szz + 32*i
            float a = 0.f;
#pragma unroll
            for (int i = 0; i < 16; ++i) {
                float4 w = wzh[i];
                float4 h4 = *(const float4*)&hL[4 * szz + 32 * i];
                a += w.x*h4.x + w.y*h4.y + w.z*h4.z + w.w*h4.w;
            }
            a += __shfl_xor(a, 1); a += __shfl_xor(a, 2); a += __shfl_xor(a, 4);
            if (szz == 0 && rz < 60) zh[rz] = a;
        }
        __syncthreads();

        // ---- phase BC (wave 0): inp -> z finalize -> softmax60 ----
        if (wv == 0) {
            if (lane < 8) {
                float v;
                if (s > 0) {
                    float a = zd[lane] + outbL[lane];
                    float m = a;
                    m = fmaxf(m, __shfl_xor(m, 1));
                    m = fmaxf(m, __shfl_xor(m, 2));
                    m = fmaxf(m, __shfl_xor(m, 4));
                    float e = __expf(a - m);
                    float ss2 = e;
                    ss2 += __shfl_xor(ss2, 1);
                    ss2 += __shfl_xor(ss2, 2);
                    ss2 += __shfl_xor(ss2, 4);
                    v = a - m - __logf(ss2);
                    if (bid == 0) dout[(s - 1) * 8 + lane] = v;
                } else {
                    v = (lane == 7) ? 1.f : 0.f;
                }
                awx[60 + lane] = v;
            }
            // z = zh + b + attn_W[:,0:8] @ inp  (same-wave LDS ordering)
            float z = -1e30f;
            if (lane < 60) {
                z = zh[lane] + attnbL[lane]
                  + wip[0].x * awx[60] + wip[0].y * awx[61]
                  + wip[0].z * awx[62] + wip[0].w * awx[63]
                  + wip[1].x * awx[64] + wip[1].y * awx[65]
                  + wip[1].z * awx[66] + wip[1].w * awx[67];
            }
            float m = z;
#pragma unroll
            for (int off = 32; off; off >>= 1) m = fmaxf(m, __shfl_xor(m, off));
            float e = (lane < 60) ? __expf(z - m) : 0.f;
            float ss2 = e;
#pragma unroll
            for (int off = 32; off; off >>= 1) ss2 += __shfl_xor(ss2, off);
            if (lane < 60) awx[lane] = e / ss2;
        }
        __syncthreads();

        // ---- phase E: o = relu(M2T^T @ [aw; inp] + comb_b), 1 dim/thread ----
        {
            float a = cbL[tid];
#pragma unroll 4
            for (int k = 0; k < 68; ++k)
                a += M2T[k][tid] * awx[k];
            xl[tid] = fmaxf(a, 0.f);
        }
        __syncthreads();

        // ---- phase F: gi = gWih @ o, k = 4*sg + 64*i ----
        {
            float a = 0.f;
#pragma unroll
            for (int i = 0; i < 8; ++i) {
                float4 w = wi8[i];
                float4 o4 = *(const float4*)&xl[4 * sg + 64 * i];
                a += w.x*o4.x + w.y*o4.y + w.z*o4.z + w.w*o4.w;
            }
            a += __shfl_xor(a, 1); a += __shfl_xor(a, 2);
            a += __shfl_xor(a, 4); a += __shfl_xor(a, 8);
            if (sg == 0 && rg < 24) gil[rg] = a;
        }
        __syncthreads();

        // ---- phase G: GRU combine + publish (8 threads) ----
        if (tid < 8) {
            float gh0 = biasg[tid] + ghl[tid];
            float gh1 = biasg[8 + tid] + ghl[8 + tid];
            float gh2 = biasg[16 + tid] + ghl[16 + tid];
            float gi0 = biasi[tid] + gil[tid];
            float gi1 = biasi[8 + tid] + gil[8 + tid];
            float gi2 = biasi[16 + tid] + gil[16 + tid];
            float r_ = sigf(gi0 + gh0);
            float z_ = sigf(gi1 + gh1);
            float n_ = tanh_f(gi2 + r_ * gh2);
            float hnew = (1.f - z_) * n_ + z_ * hL[dbase + tid];
            gstll(&hdec_p[(size_t)((s + 1) & 1) * 512 + dbase + tid], packfe(hnew, s + 1));
        }
        __syncthreads();   // protect hL/awx/xl before next-step overwrite
    }

    // epilogue: logits for s=29 (block 0 only)
    if (bid == 0) {
        {
            const ull* hs = hdec_p + (size_t)(30 & 1) * 512;
            ull v0 = gldll(hs + tid);
            while ((int)(v0 >> 32) != 30) {
                __builtin_amdgcn_s_sleep(1);
                v0 = gldll(hs + tid);
            }
            hL[tid] = lowf(v0);
        }
        __syncthreads();
        {
            float a = 0.f;
            float4 h0 = *(const float4*)&hL[4 * lane];
            float4 h1 = *(const float4*)&hL[4 * lane + 256];
            a += wo2[0].x*h0.x + wo2[0].y*h0.y + wo2[0].z*h0.z + wo2[0].w*h0.w;
            a += wo2[1].x*h1.x + wo2[1].y*h1.y + wo2[1].z*h1.z + wo2[1].w*h1.w;
#pragma unroll
            for (int off = 32; off; off >>= 1) a += __shfl_xor(a, off);
            if (lane == 0) zd[wv] = a;
        }
        __syncthreads();
        if (tid < 8) {
            float a = zd[tid] + outbL[tid];
            float m = a;
            m = fmaxf(m, __shfl_xor(m, 1));
            m = fmaxf(m, __shfl_xor(m, 2));
            m = fmaxf(m, __shfl_xor(m, 4));
            float e = __expf(a - m);
            float ss2 = e;
            ss2 += __shfl_xor(ss2, 1);
            ss2 += __shfl_xor(ss2, 2);
            ss2 += __shfl_xor(ss2, 4);
            dout[29 * 8 + tid] = a - m - __logf(ss2);
        }
    }
}

// ---------------------------------------------------------------------------
extern "C" void kernel_launch(void* const* d_in, const int* in_sizes, int n_in,
                              void* d_out, int out_size, void* d_ws, size_t ws_size,
                              hipStream_t stream) {
    (void)in_sizes; (void)n_in; (void)out_size; (void)ws_size;
    const float* data    = (const float*)d_in[0];
    const float* enc_Wih = (const float*)d_in[1];
    const float* enc_Whh = (const float*)d_in[2];
    const float* enc_bih = (const float*)d_in[3];
    const float* enc_bhh = (const float*)d_in[4];
    const float* p1f_Wih = (const float*)d_in[5];
    const float* p1f_Whh = (const float*)d_in[6];
    const float* p1f_bih = (const float*)d_in[7];
    const float* p1f_bhh = (const float*)d_in[8];
    const float* p1b_Wih = (const float*)d_in[9];
    const float* p1b_Whh = (const float*)d_in[10];
    const float* p1b_bih = (const float*)d_in[11];
    const float* p1b_bhh = (const float*)d_in[12];
    const float* p2f_Wih = (const float*)d_in[13];
    const float* p2f_Whh = (const float*)d_in[14];
    const float* p2f_bih = (const float*)d_in[15];
    const float* p2f_bhh = (const float*)d_in[16];
    const float* p2b_Wih = (const float*)d_in[17];
    const float* p2b_Whh = (const float*)d_in[18];
    const float* p2b_bih = (const float*)d_in[19];
    const float* p2b_bhh = (const float*)d_in[20];
    const float* attn_W  = (const float*)d_in[21];
    const float* attn_b  = (const float*)d_in[22];
    const float* comb_W  = (const float*)d_in[23];
    const float* comb_b  = (const float*)d_in[24];
    const float* gru_Wih = (const float*)d_in[25];
    const float* gru_Whh = (const float*)d_in[26];
    const float* gru_bih = (const float*)d_in[27];
    const float* gru_bhh = (const float*)d_in[28];
    const float* out_W   = (const float*)d_in[29];
    const float* out_b   = (const float*)d_in[30];

    float* ws = (float*)d_ws;
    // zeroed region [0 .. 501776)
    ull* fastF   = (ull*)ws;                 // 245760 floats = [2][15][4096] ull
    ull* hbufF   = (ull*)(ws + 245760);      // 245760 floats = [2][15][4096] ull
    ull* hp1     = (ull*)(ws + 491520);      // 4096 floats = [2][2][512] ull
    ull* hp2     = (ull*)(ws + 495616);      // 4096 floats
    ull* hdec_p  = (ull*)(ws + 499712);      // 2048 floats
    int* claimC  = (int*)(ws + 501760);      // 16 ints -> end 501776
    // non-zeroed scratch
    float* henc  = ws + 501776;              // 122880
    float* xp1f  = ws + 624656;              // 245760
    float* xp1b  = ws + 870416;              // 245760
    float* f1    = ws + 1116176;             // 61440
    float* b1o   = ws + 1177616;             // 61440
    float* x2    = ws + 1239056;             // 122880
    float* xp2f  = ws + 1361936;             // 122880
    float* xp2b  = ws + 1484816;             // 122880
    float* f2    = ws + 1607696;             // 30720
    float* b2o   = ws + 1638416;             // 30720
    float* ctxb  = ws + 1669136;             // 61440
    float* MgT   = ws + 1730576;             // 30720 -> end 1761296

    init_k<<<256, 256, 0, stream>>>(ws);

    enc_all<<<256, 256, 0, stream>>>(data, enc_Wih, enc_Whh, enc_bih, enc_bhh,
                                     fastF, hbufF, henc, claimC);
    gemm_xp2<<<256, 256, 0, stream>>>(henc, 120, 1024, 128,
                                      p1f_Wih, p1f_bih, p1f_bhh, xp1f,
                                      p1b_Wih, p1b_bih, p1b_bhh, xp1b);
    pyr_rec<<<128, 256, 0, stream>>>(xp1f, xp1b, p1f_Whh, p1b_Whh, hp1, f1, b1o, 120);
    x2_assemble<<<60, 256, 0, stream>>>(f1, b1o, x2);
    gemm_xp2<<<128, 256, 0, stream>>>(x2, 60, 2048, 64,
                                      p2f_Wih, p2f_bih, p2f_bhh, xp2f,
                                      p2b_Wih, p2b_bih, p2b_bhh, xp2b);
    pyr_rec<<<128, 256, 0, stream>>>(xp2f, xp2b, p2f_Whh, p2b_Whh, hp2, f2, b2o, 60);
    ctx_k<<<60, 256, 0, stream>>>(f2, b2o, ctxb, hdec_p);
    precomp_M<<<64, 256, 0, stream>>>(comb_W, ctxb, MgT);
    dec_k<<<64, 512, 0, stream>>>(attn_W, attn_b, comb_W, comb_b,
                                  gru_Wih, gru_Whh, gru_bih, gru_bhh,
                                  out_W, out_b, MgT, hdec_p,
                                  (float*)d_out);
}

// Round 10
// 1198.213 us; speedup vs baseline: 1.2038x; 1.2007x over previous
//
#include <hip/hip_runtime.h>
#include <math.h>

// Model dims: H=512 D=128 L=8 T=64 W=240 CTX=60 NSTEPS=30

typedef __attribute__((ext_vector_type(8))) short short8;
typedef __attribute__((ext_vector_type(4))) float floatx4;
typedef unsigned long long ull;

__device__ __forceinline__ float sigf(float x) { return 1.f / (1.f + __expf(-x)); }
__device__ __forceinline__ float tanh_f(float x) {
    float e = __expf(2.f * x);
    return 1.f - 2.f / (e + 1.f);
}
__device__ __forceinline__ unsigned short f2b(float x) {   // fp32 -> bf16 RNE
    unsigned u = __float_as_uint(x);
    unsigned r = (u + 0x7FFFu + ((u >> 16) & 1u)) >> 16;
    return (unsigned short)r;
}

// RELAXED agent-scope atomics only (acquire/release emit buffer_inv/wbl2 on
// gfx950 and trash the XCD L2). Cross-block payloads are {epoch|data} ull
// words polled directly (data+readiness in one MALL round trip), batch-polled.
// R14: the R12/R13 XCD-local "fast path" is REMOVED (falsified twice: volatile
// loads spin on stale L1 lines -> low FETCH + high time; dual-publish doubles
// WRITE traffic; credit-gating did not recover R11 perf). enc exchange
// reverts to the proven R11 single-MALL-path form. Gains this round are
// structural: 2 launches removed (x2_assemble fused into stage-2 GEMM;
// ctx_k folded into precomp_M) and pyr_rec loses one barrier/step via
// intra-wave shuffle reduction.
__device__ __forceinline__ float gld(const float* p) {
    return __hip_atomic_load(p, __ATOMIC_RELAXED, __HIP_MEMORY_SCOPE_AGENT);
}
__device__ __forceinline__ void gst(float* p, float v) {
    __hip_atomic_store(p, v, __ATOMIC_RELAXED, __HIP_MEMORY_SCOPE_AGENT);
}
__device__ __forceinline__ ull gldll(const ull* p) {
    return __hip_atomic_load(p, __ATOMIC_RELAXED, __HIP_MEMORY_SCOPE_AGENT);
}
__device__ __forceinline__ void gstll(ull* p, ull v) {
    __hip_atomic_store(p, v, __ATOMIC_RELAXED, __HIP_MEMORY_SCOPE_AGENT);
}
__device__ __forceinline__ ull packfe(float d, int ep) {
    return ((ull)(unsigned)ep << 32) | (ull)__float_as_uint(d);
}
__device__ __forceinline__ float lowf(ull v) { return __uint_as_float((unsigned)v); }

// ---------------------------------------------------------------------------
// init: zero [hbufF(245760f) | hp1(4096) | hp2(4096) | hdec(2048)] = 256000 f
// ---------------------------------------------------------------------------
__global__ void init_k(float* __restrict__ ws) {
    for (int i = blockIdx.x * blockDim.x + threadIdx.x; i < 256000; i += gridDim.x * blockDim.x)
        ws[i] = 0.f;
}

// ---------------------------------------------------------------------------
// Encoder, ONE persistent launch, 64 steps, bf16 MFMA (R11 verbatim).
// ---------------------------------------------------------------------------
__global__ void __launch_bounds__(256, 1) enc_all(
    const float* __restrict__ data,
    const float* __restrict__ Wih, const float* __restrict__ Whh,
    const float* __restrict__ bih, const float* __restrict__ bhh,
    ull* __restrict__ hbufF,        // [2][15][4096] {epoch|bf16x2}
    float* __restrict__ henc)       // [240][512] fp32 final h
{
    __shared__ short act2[20 * 64 * 8];
    __shared__ float gw[4][640];
    __shared__ float cs[512];
    __shared__ short hw[4][16][8];
    __shared__ float biasL[4][4][8];

    const int tid = threadIdx.x;
    const int fg = blockIdx.x >> 4, ds = blockIdx.x & 15;
    const int w = tid >> 6, lane = tid & 63;
    const int n = lane & 15, q = lane >> 4;

    short8 bfrag[2][20];
#pragma unroll
    for (int nt = 0; nt < 2; ++nt) {
        int rr = nt * 16 + n;
        int g = rr >> 3, dp = rr & 7;
        int grow = g * 512 + ds * 32 + w * 8 + dp;
#pragma unroll
        for (int kt = 0; kt < 20; ++kt) {
            int k0 = kt * 32 + q * 8;
            const float* src = (k0 < 512) ? (Whh + (size_t)grow * 512 + k0)
                                          : (Wih + (size_t)grow * 128 + (k0 - 512));
            float4 lo = *(const float4*)src;
            float4 hi = *(const float4*)(src + 4);
            short8 bf;
            bf[0] = (short)f2b(lo.x); bf[1] = (short)f2b(lo.y);
            bf[2] = (short)f2b(lo.z); bf[3] = (short)f2b(lo.w);
            bf[4] = (short)f2b(hi.x); bf[5] = (short)f2b(hi.y);
            bf[6] = (short)f2b(hi.z); bf[7] = (short)f2b(hi.w);
            bfrag[nt][kt] = bf;
        }
    }
    if (tid < 128) {
        int w2 = tid >> 5, rr = tid & 31;
        int g = rr >> 3, dp = rr & 7;
        int grow = g * 512 + ds * 32 + w2 * 8 + dp;
        biasL[w2][g][dp] = bih[grow] + bhh[grow];
    }
    for (int i = tid; i < 512; i += 256) cs[i] = 0.f;
    __syncthreads();

    unsigned* a2u = (unsigned*)act2;

    for (int t = 0; t < 64; ++t) {
        // x prefetch FIRST: global loads issue, latency hides under the h poll
        const int kt2 = tid >> 6, l2 = tid & 63, f2v = l2 & 15, q2 = l2 >> 4;
        const float* xs = data + ((size_t)t * 240 + fg * 16 + f2v) * 128 + kt2 * 32 + q2 * 8;
        float4 lo = *(const float4*)xs;
        float4 hi = *(const float4*)(xs + 4);

        // h gather: batch-poll 16 {epoch|bf16x2} words (ONE MALL window)
        {
            const ull* hsrc = hbufF + (size_t)((t & 1) * 15 + fg) * 4096;
            ull v[16];
            for (;;) {
                bool ok = true;
#pragma unroll
                for (int k2 = 0; k2 < 16; ++k2) {
                    v[k2] = gldll(hsrc + tid + 256 * k2);
                    ok &= ((int)(v[k2] >> 32) == t);
                }
                if (ok) break;
                __builtin_amdgcn_s_sleep(1);
            }
#pragma unroll
            for (int k2 = 0; k2 < 16; ++k2)
                a2u[tid + 256 * k2] = (unsigned)v[k2];
        }
        {
            short8 xp;
            xp[0] = (short)f2b(lo.x); xp[1] = (short)f2b(lo.y);
            xp[2] = (short)f2b(lo.z); xp[3] = (short)f2b(lo.w);
            xp[4] = (short)f2b(hi.x); xp[5] = (short)f2b(hi.y);
            xp[6] = (short)f2b(hi.z); xp[7] = (short)f2b(hi.w);
            *(short8*)&act2[((16 + kt2) * 64 + l2) * 8] = xp;
        }
        __syncthreads();

        floatx4 acc0 = {0.f, 0.f, 0.f, 0.f};
        floatx4 acc1 = {0.f, 0.f, 0.f, 0.f};
#pragma unroll
        for (int kt = 0; kt < 20; ++kt) {
            short8 a = *(short8*)&act2[(kt * 64 + lane) * 8];
            acc0 = __builtin_amdgcn_mfma_f32_16x16x32_bf16(a, bfrag[0][kt], acc0, 0, 0, 0);
            acc1 = __builtin_amdgcn_mfma_f32_16x16x32_bf16(a, bfrag[1][kt], acc1, 0, 0, 0);
        }
        *(floatx4*)&gw[w][(0 * 16 + n) * 20 + 4 * q] = acc0;
        *(floatx4*)&gw[w][(1 * 16 + n) * 20 + 4 * q] = acc1;

        int nb = (t + 1) & 1;
#pragma unroll
        for (int it = 0; it < 2; ++it) {
            int f = lane & 15, dp = q + 4 * it;
            float gi = gw[w][(0 * 8 + dp) * 20 + f] + biasL[w][0][dp];
            float gf = gw[w][(1 * 8 + dp) * 20 + f] + biasL[w][1][dp];
            float gg = gw[w][(2 * 8 + dp) * 20 + f] + biasL[w][2][dp];
            float go = gw[w][(3 * 8 + dp) * 20 + f] + biasL[w][3][dp];
            int ci = f * 32 + w * 8 + dp;
            float cc = cs[ci];
            float cn = sigf(gf) * cc + sigf(gi) * tanh_f(gg);
            float hn = sigf(go) * tanh_f(cn);
            cs[ci] = cn;
            hw[w][f][dp] = (short)f2b(hn);
            if (t == 63)
                gst(&henc[(size_t)(fg * 16 + f) * 512 + ds * 32 + w * 8 + dp], hn);
        }
        if (lane < 16) {
            const unsigned* hwu = (const unsigned*)&hw[w][lane][0];
            ull* dst = hbufF + (size_t)(nb * 15 + fg) * 4096 + (ds * 64 + w * 16 + lane) * 4;
            const ull ep = ((ull)(unsigned)(t + 1)) << 32;
#pragma unroll
            for (int r = 0; r < 4; ++r)
                gstll(dst + r, ep | (ull)hwu[r]);
        }
        __syncthreads();
    }
}

// ---------------------------------------------------------------------------
// xp GEMM stage 1 (A = henc), F/B pair fused (unchanged).
// ---------------------------------------------------------------------------
__global__ void __launch_bounds__(256) gemm_xp2(
    const float* __restrict__ A, int M, int K, int halfgrid,
    const float* __restrict__ WvF, const float* __restrict__ baF,
    const float* __restrict__ bbF, float* __restrict__ CF,
    const float* __restrict__ WvB, const float* __restrict__ baB,
    const float* __restrict__ bbB, float* __restrict__ CB)
{
    __shared__ float At[16][66];
    __shared__ float Wt[128][66];
    const int tid = threadIdx.x;
    int bgl = blockIdx.x;
    const int rev = (bgl >= halfgrid) ? 1 : 0;
    if (rev) bgl -= halfgrid;
    const float* Wv = rev ? WvB : WvF;
    const float* ba = rev ? baB : baF;
    const float* bb = rev ? bbB : bbF;
    float* C        = rev ? CB : CF;

    const int nt = bgl & 15, mt = bgl >> 4;
    const int rp = tid >> 2, fq = tid & 3;
    const int lr0 = 2 * rp, lr1 = lr0 + 1;
    const int n0 = nt * 128 + lr0, n1 = n0 + 1;

    float acc0[4], acc1[4];
    {
        float b0 = ba[n0] + bb[n0], b1 = ba[n1] + bb[n1];
#pragma unroll
        for (int j = 0; j < 4; ++j) { acc0[j] = b0; acc1[j] = b1; }
    }

    for (int kt = 0; kt < K; kt += 64) {
        {
            int f = tid >> 4, c4 = tid & 15;
            int m = mt * 16 + f;
            float4 v = make_float4(0.f, 0.f, 0.f, 0.f);
            if (m < M) {
                int ar = rev ? (M - 1 - m) : m;
                v = ((const float4*)(A + (size_t)ar * K + kt))[c4];
            }
            At[f][c4 * 4 + 0] = v.x; At[f][c4 * 4 + 1] = v.y;
            At[f][c4 * 4 + 2] = v.z; At[f][c4 * 4 + 3] = v.w;
        }
        for (int i = tid; i < 2048; i += 256) {
            int lr = i >> 4, c4 = i & 15;
            float4 v = ((const float4*)(Wv + (size_t)(nt * 128 + lr) * K + kt))[c4];
            Wt[lr][c4 * 4 + 0] = v.x; Wt[lr][c4 * 4 + 1] = v.y;
            Wt[lr][c4 * 4 + 2] = v.z; Wt[lr][c4 * 4 + 3] = v.w;
        }
        __syncthreads();
        const float2* w0p = (const float2*)(&Wt[lr0][0]);
        const float2* w1p = (const float2*)(&Wt[lr1][0]);
#pragma unroll 8
        for (int kh = 0; kh < 32; ++kh) {
            float2 w0 = w0p[kh], w1 = w1p[kh];
#pragma unroll
            for (int j = 0; j < 4; ++j) {
                float2 av = ((const float2*)(&At[4 * fq + j][0]))[kh];
                acc0[j] += w0.x * av.x + w0.y * av.y;
                acc1[j] += w1.x * av.x + w1.y * av.y;
            }
        }
        __syncthreads();
    }
#pragma unroll
    for (int j = 0; j < 4; ++j) {
        int m = mt * 16 + 4 * fq + j;
        if (m < M) {
            C[(size_t)m * 2048 + n0] = acc0[j];
            C[(size_t)m * 2048 + n1] = acc1[j];
        }
    }
}

// ---------------------------------------------------------------------------
// R14: xp GEMM stage 2 reading the virtual x2 directly from f1/b1o:
// x2[j][k] with k = seg*512 + r  ->  src = (seg&1 ? b1o : f1),
// row = 2*j + (seg>>1). Eliminates the x2_assemble kernel + buffer.
// M = 60, K = 2048. Grid = 2*halfgrid (F then B/reversed).
// ---------------------------------------------------------------------------
__global__ void __launch_bounds__(256) gemm_x2(
    const float* __restrict__ f1, const float* __restrict__ b1o,
    int M, int K, int halfgrid,
    const float* __restrict__ WvF, const float* __restrict__ baF,
    const float* __restrict__ bbF, float* __restrict__ CF,
    const float* __restrict__ WvB, const float* __restrict__ baB,
    const float* __restrict__ bbB, float* __restrict__ CB)
{
    __shared__ float At[16][66];
    __shared__ float Wt[128][66];
    const int tid = threadIdx.x;
    int bgl = blockIdx.x;
    const int rev = (bgl >= halfgrid) ? 1 : 0;
    if (rev) bgl -= halfgrid;
    const float* Wv = rev ? WvB : WvF;
    const float* ba = rev ? baB : baF;
    const float* bb = rev ? bbB : bbF;
    float* C        = rev ? CB : CF;

    const int nt = bgl & 15, mt = bgl >> 4;
    const int rp = tid >> 2, fq = tid & 3;
    const int lr0 = 2 * rp, lr1 = lr0 + 1;
    const int n0 = nt * 128 + lr0, n1 = n0 + 1;

    float acc0[4], acc1[4];
    {
        float b0 = ba[n0] + bb[n0], b1 = ba[n1] + bb[n1];
#pragma unroll
        for (int j = 0; j < 4; ++j) { acc0[j] = b0; acc1[j] = b1; }
    }

    for (int kt = 0; kt < K; kt += 64) {
        {
            int f = tid >> 4, c4 = tid & 15;
            int m = mt * 16 + f;
            float4 v = make_float4(0.f, 0.f, 0.f, 0.f);
            if (m < M) {
                int ar = rev ? (M - 1 - m) : m;
                int seg = kt >> 9;              // 0..3 (K=2048)
                int r = (kt & 511) + 4 * c4;    // within 512-block
                const float* src = (seg & 1) ? b1o : f1;
                int srow = 2 * ar + (seg >> 1);
                v = *(const float4*)&src[(size_t)srow * 512 + r];
            }
            At[f][c4 * 4 + 0] = v.x; At[f][c4 * 4 + 1] = v.y;
            At[f][c4 * 4 + 2] = v.z; At[f][c4 * 4 + 3] = v.w;
        }
        for (int i = tid; i < 2048; i += 256) {
            int lr = i >> 4, c4 = i & 15;
            float4 v = ((const float4*)(Wv + (size_t)(nt * 128 + lr) * K + kt))[c4];
            Wt[lr][c4 * 4 + 0] = v.x; Wt[lr][c4 * 4 + 1] = v.y;
            Wt[lr][c4 * 4 + 2] = v.z; Wt[lr][c4 * 4 + 3] = v.w;
        }
        __syncthreads();
        const float2* w0p = (const float2*)(&Wt[lr0][0]);
        const float2* w1p = (const float2*)(&Wt[lr1][0]);
#pragma unroll 8
        for (int kh = 0; kh < 32; ++kh) {
            float2 w0 = w0p[kh], w1 = w1p[kh];
#pragma unroll
            for (int j = 0; j < 4; ++j) {
                float2 av = ((const float2*)(&At[4 * fq + j][0]))[kh];
                acc0[j] += w0.x * av.x + w0.y * av.y;
                acc1[j] += w1.x * av.x + w1.y * av.y;
            }
        }
        __syncthreads();
    }
#pragma unroll
    for (int j = 0; j < 4; ++j) {
        int m = mt * 16 + 4 * fq + j;
        if (m < M) {
            C[(size_t)m * 2048 + n0] = acc0[j];
            C[(size_t)m * 2048 + n1] = acc1[j];
        }
    }
}

// ---------------------------------------------------------------------------
// Pyramidal bi-LSTM. R14: row=tid>>3 / seg=tid&7 mapping so the 8-seg
// reduction is an intra-wave shfl_xor(1,2,4) — removes the red[32][9] LDS
// round-trip and one barrier (3 barriers/step instead of 4). LDS reads at
// 4*seg + 32*i are conflict-free (8 float4 starts span 128B).
// ---------------------------------------------------------------------------
__global__ void __launch_bounds__(256, 1) pyr_rec(
    const float* __restrict__ xpF, const float* __restrict__ xpB,
    const float* __restrict__ WhhF, const float* __restrict__ WhhB,
    ull* __restrict__ hp,      // [dir][2][512]
    float* __restrict__ outF, float* __restrict__ outB,
    int steps)
{
    const int tid = threadIdx.x;
    const int dir = blockIdx.x >> 6, blk = blockIdx.x & 63;
    const float* xp  = dir ? xpB : xpF;
    const float* Whh = dir ? WhhB : WhhF;
    float* outp = dir ? outB : outF;
    ull* hpd = hp + (size_t)dir * 1024;

    __shared__ __align__(16) float hcur[512];
    __shared__ float gv[32];

    const int row = tid >> 3, seg = tid & 7;   // 32 rows x 8 segs
    const int grow = (row >> 3) * 512 + blk * 8 + (row & 7);
    float4 wl4[16];
#pragma unroll
    for (int j = 0; j < 16; ++j)
        wl4[j] = *(const float4*)&Whh[(size_t)grow * 512 + 4 * seg + 32 * j];

    float creg = 0.f;
    __syncthreads();

    for (int t = 0; t < steps; ++t) {
        float xg = 0.f;
        if (seg == 0) xg = xp[(size_t)t * 2048 + grow];   // prefetch (no h dep)
        {
            const ull* base = hpd + (size_t)(t & 1) * 512;
            ull v0 = gldll(base + tid), v1 = gldll(base + tid + 256);
            while (((int)(v0 >> 32) != t) | ((int)(v1 >> 32) != t)) {
                __builtin_amdgcn_s_sleep(1);
                v0 = gldll(base + tid);
                v1 = gldll(base + tid + 256);
            }
            hcur[tid]       = lowf(v0);
            hcur[tid + 256] = lowf(v1);
        }
        __syncthreads();

        float a = 0.f;
#pragma unroll
        for (int j = 0; j < 16; ++j) {
            float4 w = wl4[j];
            float4 h4 = *(const float4*)&hcur[4 * seg + 32 * j];
            a += w.x*h4.x + w.y*h4.y + w.z*h4.z + w.w*h4.w;
        }
        a += __shfl_xor(a, 1);
        a += __shfl_xor(a, 2);
        a += __shfl_xor(a, 4);
        if (seg == 0) gv[row] = a + xg;
        __syncthreads();

        if (tid < 8) {
            float i_ = sigf(gv[tid]), f_ = sigf(gv[8 + tid]);
            float g_ = tanh_f(gv[16 + tid]), o_ = sigf(gv[24 + tid]);
            creg = f_ * creg + i_ * g_;
            float hn = o_ * tanh_f(creg);
            int d = blk * 8 + tid;
            gstll(&hpd[((t + 1) & 1) * 512 + d], packfe(hn, t + 1));
            int row2 = dir ? (steps - 1 - t) : t;
            outp[(size_t)row2 * 512 + d] = hn;
        }
        __syncthreads();
    }
}

// ---------------------------------------------------------------------------
// R14: precompute M^T directly from f2/b2o (virtual ctx[j] = [f2[j]; b2o[j]])
// -> MgT[60][512]. Block 0 also publishes hdec epoch-0 (was ctx_k's job).
// ---------------------------------------------------------------------------
__global__ void __launch_bounds__(256) precomp_M(
    const float* __restrict__ comb_W,   // [512][1032]
    const float* __restrict__ f2,       // [60][512]
    const float* __restrict__ b2o,      // [60][512]
    float* __restrict__ MgT,            // [60][512]
    ull* __restrict__ hdec_p)           // [2][512]
{
    __shared__ float cw[8 * 1024];      // 32 KB: comb_W rows d0..d0+8, cols 8..1032
    const int tid = threadIdx.x, d0 = blockIdx.x * 8;
    for (int i = tid; i < 2048; i += 256) {
        int r = i >> 8, c4 = i & 255;
        float4 v = *(const float4*)&comb_W[(size_t)(d0 + r) * 1032 + 8 + 4 * c4];
        *(float4*)&cw[r * 1024 + 4 * c4] = v;
    }
    if (blockIdx.x == 0) {
        for (int i = tid; i < 512; i += 256)
            hdec_p[i] = packfe(f2[59 * 512 + i], 0);
    }
    __syncthreads();
    for (int o = tid; o < 480; o += 256) {
        int dl = o / 60, j = o % 60;
        const float4* cp0 = (const float4*)&cw[dl * 1024];          // k 0..511
        const float4* cp1 = (const float4*)&cw[dl * 1024 + 512];    // k 512..1023
        const float4* xf = (const float4*)(f2 + (size_t)j * 512);
        const float4* xb = (const float4*)(b2o + (size_t)j * 512);
        float a = 0.f;
#pragma unroll 4
        for (int k = 0; k < 128; ++k) {
            float4 w = cp0[k], x = xf[k];
            a += w.x * x.x + w.y * x.y + w.z * x.z + w.w * x.w;
        }
#pragma unroll 4
        for (int k = 0; k < 128; ++k) {
            float4 w = cp1[k], x = xb[k];
            a += w.x * x.x + w.y * x.y + w.z * x.z + w.w * x.w;
        }
        MgT[(size_t)j * 512 + (d0 + dl)] = a;
    }
}

// ---------------------------------------------------------------------------
// Decoder (unchanged from R11): 64 blocks x 512 threads, register weights,
// shuffle reductions, conflict-free LDS mappings, 1-word/thread h poll.
// ---------------------------------------------------------------------------
__global__ void __launch_bounds__(512, 1) dec_k(
    const float* __restrict__ attn_W, const float* __restrict__ attn_b,
    const float* __restrict__ comb_W, const float* __restrict__ comb_b,
    const float* __restrict__ gWih, const float* __restrict__ gWhh,
    const float* __restrict__ gbih, const float* __restrict__ gbhh,
    const float* __restrict__ outW, const float* __restrict__ outb,
    const float* __restrict__ MgT,  // [60][512]
    ull* __restrict__ hdec_p,       // [2][512]
    float* __restrict__ dout)
{
    const int tid = threadIdx.x, bid = blockIdx.x;   // 64 blocks x 512 thr
    const int lane = tid & 63, wv = tid >> 6;
    const int dbase = bid * 8;

    __shared__ float M2T[68][512];                   // rows: [M(60) | Minp(8)]
    __shared__ __align__(16) float hL[520];          // h(512) + pad
    __shared__ __align__(16) float xl[512];          // o
    __shared__ __align__(16) float awx[68];          // [aw(60); inp(8)]
    __shared__ float zd[8], zh[64];
    __shared__ float ghl[24], gil[24];
    __shared__ float biasg[24], biasi[24];
    __shared__ float cbL[512];
    __shared__ float attnbL[64], outbL[8];

    // row/seg partitions
    const int rg = tid >> 4, sg = tid & 15;   // gh/gi: 24(32) rows x 16 segs
    const int rz = tid >> 3, szz = tid & 7;   // z_h: 60(64) rows x 8 segs

    // ---- weights to registers (interleaved k-mappings) ----
    float4 wo2[2];                  // logits row wv: k = 4*lane + 256*i
    float4 wg8[8], wi8[8];          // gh/gi row rg:  k = 4*sg + 64*i
    float4 wzh[16];                 // z_h row rz:    k = 4*szz + 32*i
    float4 wip[2];                  // z inp-part (row tid<60)
    {
        const float* wp = outW + (size_t)wv * 512 + 4 * lane;
        wo2[0] = *(const float4*)wp;
        wo2[1] = *(const float4*)(wp + 256);
    }
    {
        int rr = (rg < 24) ? rg : 23;
        size_t grow = (size_t)((rr >> 3) * 512 + dbase + (rr & 7)) * 512 + 4 * sg;
#pragma unroll
        for (int i = 0; i < 8; ++i) {
            wg8[i] = *(const float4*)&gWhh[grow + 64 * i];
            wi8[i] = *(const float4*)&gWih[grow + 64 * i];
        }
    }
    {
        int rr = (rz < 60) ? rz : 59;
        size_t base = (size_t)rr * 520 + 8 + 4 * szz;
#pragma unroll
        for (int i = 0; i < 16; ++i)
            wzh[i] = *(const float4*)&attn_W[base + 32 * i];
    }
    {
        int rr = (tid < 60) ? tid : 59;
        wip[0] = *(const float4*)&attn_W[(size_t)rr * 520 + 0];
        wip[1] = *(const float4*)&attn_W[(size_t)rr * 520 + 4];
    }
    if (tid < 24) {
        int g2 = (tid >> 3) * 512 + dbase + (tid & 7);
        biasg[tid] = gbhh[g2];
        biasi[tid] = gbih[g2];
    }
    cbL[tid] = comb_b[tid];
    if (tid < 64) attnbL[tid] = (tid < 60) ? attn_b[tid] : 0.f;
    if (tid < 8) outbL[tid] = outb[tid];
    // M2T rows 0..59 from MgT (coalesced), rows 60..67 = comb_W cols 0..8
    for (int i = tid; i < 7680; i += 512) {
        int j = i >> 7, c4 = i & 127;
        *(float4*)&M2T[j][4 * c4] = *(const float4*)&MgT[(size_t)j * 512 + 4 * c4];
    }
    for (int i = tid; i < 4096; i += 512) {
        int r = i >> 3, c = i & 7;
        M2T[60 + c][r] = comb_W[(size_t)r * 1032 + c];
    }
    __syncthreads();

    for (int s = 0; s < 30; ++s) {
        // ---- cross-block hop: h (slot s&1, epoch s), 1 word/thread ----
        {
            const ull* hs = hdec_p + (size_t)(s & 1) * 512;
            ull v0 = gldll(hs + tid);
            while ((int)(v0 >> 32) != s) {
                __builtin_amdgcn_s_sleep(1);
                v0 = gldll(hs + tid);
            }
            hL[tid] = lowf(v0);
        }
        __syncthreads();

        // ---- phase A: three h-matvec partials + shuffle reductions ----
        {   // logits: one wave per row, contiguous 16B-stride reads
            float a = 0.f;
            float4 h0 = *(const float4*)&hL[4 * lane];
            float4 h1 = *(const float4*)&hL[4 * lane + 256];
            a += wo2[0].x*h0.x + wo2[0].y*h0.y + wo2[0].z*h0.z + wo2[0].w*h0.w;
            a += wo2[1].x*h1.x + wo2[1].y*h1.y + wo2[1].z*h1.z + wo2[1].w*h1.w;
#pragma unroll
            for (int off = 32; off; off >>= 1) a += __shfl_xor(a, off);
            if (lane == 0) zd[wv] = a;
        }
        {   // gh: 16 segs, k = 4*sg + 64*i
            float a = 0.f;
#pragma unroll
            for (int i = 0; i < 8; ++i) {
                float4 w = wg8[i];
                float4 h4 = *(const float4*)&hL[4 * sg + 64 * i];
                a += w.x*h4.x + w.y*h4.y + w.z*h4.z + w.w*h4.w;
            }
            a += __shfl_xor(a, 1); a += __shfl_xor(a, 2);
            a += __shfl_xor(a, 4); a += __shfl_xor(a, 8);
            if (sg == 0 && rg < 24) ghl[rg] = a;
        }
        {   // z_h: 8 segs, k = 4*szz + 32*i
            float a = 0.f;
#pragma unroll
            for (int i = 0; i < 16; ++i) {
                float4 w = wzh[i];
                float4 h4 = *(const float4*)&hL[4 * szz + 32 * i];
                a += w.x*h4.x + w.y*h4.y + w.z*h4.z + w.w*h4.w;
            }
            a += __shfl_xor(a, 1); a += __shfl_xor(a, 2); a += __shfl_xor(a, 4);
            if (szz == 0 && rz < 60) zh[rz] = a;
        }
        __syncthreads();

        // ---- phase BC (wave 0): inp -> z finalize -> softmax60 ----
        if (wv == 0) {
            if (lane < 8) {
                float v;
                if (s > 0) {
                    float a = zd[lane] + outbL[lane];
                    float m = a;
                    m = fmaxf(m, __shfl_xor(m, 1));
                    m = fmaxf(m, __shfl_xor(m, 2));
                    m = fmaxf(m, __shfl_xor(m, 4));
                    float e = __expf(a - m);
                    float ss2 = e;
                    ss2 += __shfl_xor(ss2, 1);
                    ss2 += __shfl_xor(ss2, 2);
                    ss2 += __shfl_xor(ss2, 4);
                    v = a - m - __logf(ss2);
                    if (bid == 0) dout[(s - 1) * 8 + lane] = v;
                } else {
                    v = (lane == 7) ? 1.f : 0.f;
                }
                awx[60 + lane] = v;
            }
            // z = zh + b + attn_W[:,0:8] @ inp  (same-wave LDS ordering)
            float z = -1e30f;
            if (lane < 60) {
                z = zh[lane] + attnbL[lane]
                  + wip[0].x * awx[60] + wip[0].y * awx[61]
                  + wip[0].z * awx[62] + wip[0].w * awx[63]
                  + wip[1].x * awx[64] + wip[1].y * awx[65]
                  + wip[1].z * awx[66] + wip[1].w * awx[67];
            }
            float m = z;
#pragma unroll
            for (int off = 32; off; off >>= 1) m = fmaxf(m, __shfl_xor(m, off));
            float e = (lane < 60) ? __expf(z - m) : 0.f;
            float ss2 = e;
#pragma unroll
            for (int off = 32; off; off >>= 1) ss2 += __shfl_xor(ss2, off);
            if (lane < 60) awx[lane] = e / ss2;
        }
        __syncthreads();

        // ---- phase E: o = relu(M2T^T @ [aw; inp] + comb_b), 1 dim/thread ----
        {
            float a = cbL[tid];
#pragma unroll 4
            for (int k = 0; k < 68; ++k)
                a += M2T[k][tid] * awx[k];
            xl[tid] = fmaxf(a, 0.f);
        }
        __syncthreads();

        // ---- phase F: gi = gWih @ o, k = 4*sg + 64*i ----
        {
            float a = 0.f;
#pragma unroll
            for (int i = 0; i < 8; ++i) {
                float4 w = wi8[i];
                float4 o4 = *(const float4*)&xl[4 * sg + 64 * i];
                a += w.x*o4.x + w.y*o4.y + w.z*o4.z + w.w*o4.w;
            }
            a += __shfl_xor(a, 1); a += __shfl_xor(a, 2);
            a += __shfl_xor(a, 4); a += __shfl_xor(a, 8);
            if (sg == 0 && rg < 24) gil[rg] = a;
        }
        __syncthreads();

        // ---- phase G: GRU combine + publish (8 threads) ----
        if (tid < 8) {
            float gh0 = biasg[tid] + ghl[tid];
            float gh1 = biasg[8 + tid] + ghl[8 + tid];
            float gh2 = biasg[16 + tid] + ghl[16 + tid];
            float gi0 = biasi[tid] + gil[tid];
            float gi1 = biasi[8 + tid] + gil[8 + tid];
            float gi2 = biasi[16 + tid] + gil[16 + tid];
            float r_ = sigf(gi0 + gh0);
            float z_ = sigf(gi1 + gh1);
            float n_ = tanh_f(gi2 + r_ * gh2);
            float hnew = (1.f - z_) * n_ + z_ * hL[dbase + tid];
            gstll(&hdec_p[(size_t)((s + 1) & 1) * 512 + dbase + tid], packfe(hnew, s + 1));
        }
        __syncthreads();   // protect hL/awx/xl before next-step overwrite
    }

    // epilogue: logits for s=29 (block 0 only)
    if (bid == 0) {
        {
            const ull* hs = hdec_p + (size_t)(30 & 1) * 512;
            ull v0 = gldll(hs + tid);
            while ((int)(v0 >> 32) != 30) {
                __builtin_amdgcn_s_sleep(1);
                v0 = gldll(hs + tid);
            }
            hL[tid] = lowf(v0);
        }
        __syncthreads();
        {
            float a = 0.f;
            float4 h0 = *(const float4*)&hL[4 * lane];
            float4 h1 = *(const float4*)&hL[4 * lane + 256];
            a += wo2[0].x*h0.x + wo2[0].y*h0.y + wo2[0].z*h0.z + wo2[0].w*h0.w;
            a += wo2[1].x*h1.x + wo2[1].y*h1.y + wo2[1].z*h1.z + wo2[1].w*h1.w;
#pragma unroll
            for (int off = 32; off; off >>= 1) a += __shfl_xor(a, off);
            if (lane == 0) zd[wv] = a;
        }
        __syncthreads();
        if (tid < 8) {
            float a = zd[tid] + outbL[tid];
            float m = a;
            m = fmaxf(m, __shfl_xor(m, 1));
            m = fmaxf(m, __shfl_xor(m, 2));
            m = fmaxf(m, __shfl_xor(m, 4));
            float e = __expf(a - m);
            float ss2 = e;
            ss2 += __shfl_xor(ss2, 1);
            ss2 += __shfl_xor(ss2, 2);
            ss2 += __shfl_xor(ss2, 4);
            dout[29 * 8 + tid] = a - m - __logf(ss2);
        }
    }
}

// ---------------------------------------------------------------------------
extern "C" void kernel_launch(void* const* d_in, const int* in_sizes, int n_in,
                              void* d_out, int out_size, void* d_ws, size_t ws_size,
                              hipStream_t stream) {
    (void)in_sizes; (void)n_in; (void)out_size; (void)ws_size;
    const float* data    = (const float*)d_in[0];
    const float* enc_Wih = (const float*)d_in[1];
    const float* enc_Whh = (const float*)d_in[2];
    const float* enc_bih = (const float*)d_in[3];
    const float* enc_bhh = (const float*)d_in[4];
    const float* p1f_Wih = (const float*)d_in[5];
    const float* p1f_Whh = (const float*)d_in[6];
    const float* p1f_bih = (const float*)d_in[7];
    const float* p1f_bhh = (const float*)d_in[8];
    const float* p1b_Wih = (const float*)d_in[9];
    const float* p1b_Whh = (const float*)d_in[10];
    const float* p1b_bih = (const float*)d_in[11];
    const float* p1b_bhh = (const float*)d_in[12];
    const float* p2f_Wih = (const float*)d_in[13];
    const float* p2f_Whh = (const float*)d_in[14];
    const float* p2f_bih = (const float*)d_in[15];
    const float* p2f_bhh = (const float*)d_in[16];
    const float* p2b_Wih = (const float*)d_in[17];
    const float* p2b_Whh = (const float*)d_in[18];
    const float* p2b_bih = (const float*)d_in[19];
    const float* p2b_bhh = (const float*)d_in[20];
    const float* attn_W  = (const float*)d_in[21];
    const float* attn_b  = (const float*)d_in[22];
    const float* comb_W  = (const float*)d_in[23];
    const float* comb_b  = (const float*)d_in[24];
    const float* gru_Wih = (const float*)d_in[25];
    const float* gru_Whh = (const float*)d_in[26];
    const float* gru_bih = (const float*)d_in[27];
    const float* gru_bhh = (const float*)d_in[28];
    const float* out_W   = (const float*)d_in[29];
    const float* out_b   = (const float*)d_in[30];

    float* ws = (float*)d_ws;
    // zeroed region [0 .. 256000)
    ull* hbufF   = (ull*)ws;                 // 245760 floats = [2][15][4096] ull
    ull* hp1     = (ull*)(ws + 245760);      // 4096 floats = [2][2][512] ull
    ull* hp2     = (ull*)(ws + 249856);      // 4096 floats
    ull* hdec_p  = (ull*)(ws + 253952);      // 2048 floats -> end 256000
    // non-zeroed scratch
    float* henc  = ws + 256000;              // 122880
    float* xp1f  = ws + 378880;              // 245760
    float* xp1b  = ws + 624640;              // 245760
    float* f1    = ws + 870400;              // 61440
    float* b1o   = ws + 931840;              // 61440
    float* xp2f  = ws + 993280;              // 122880
    float* xp2b  = ws + 1116160;             // 122880
    float* f2    = ws + 1239040;             // 30720
    float* b2o   = ws + 1269760;             // 30720
    float* MgT   = ws + 1300480;             // 30720 -> end 1331200

    init_k<<<256, 256, 0, stream>>>(ws);

    enc_all<<<240, 256, 0, stream>>>(data, enc_Wih, enc_Whh, enc_bih, enc_bhh,
                                     hbufF, henc);
    gemm_xp2<<<256, 256, 0, stream>>>(henc, 120, 1024, 128,
                                      p1f_Wih, p1f_bih, p1f_bhh, xp1f,
                                      p1b_Wih, p1b_bih, p1b_bhh, xp1b);
    pyr_rec<<<128, 256, 0, stream>>>(xp1f, xp1b, p1f_Whh, p1b_Whh, hp1, f1, b1o, 120);
    gemm_x2<<<128, 256, 0, stream>>>(f1, b1o, 60, 2048, 64,
                                     p2f_Wih, p2f_bih, p2f_bhh, xp2f,
                                     p2b_Wih, p2b_bih, p2b_bhh, xp2b);
    pyr_rec<<<128, 256, 0, stream>>>(xp2f, xp2b, p2f_Whh, p2b_Whh, hp2, f2, b2o, 60);
    precomp_M<<<64, 256, 0, stream>>>(comb_W, f2, b2o, MgT, hdec_p);
    dec_k<<<64, 512, 0, stream>>>(attn_W, attn_b, comb_W, comb_b,
                                  gru_Wih, gru_Whh, gru_bih, gru_bhh,
                                  out_W, out_b, MgT, hdec_p,
                                  (float*)d_out);
}

// Round 11
// 1186.735 us; speedup vs baseline: 1.2155x; 1.0097x over previous
//
#include <hip/hip_runtime.h>
#include <math.h>

// Model dims: H=512 D=128 L=8 T=64 W=240 CTX=60 NSTEPS=30

typedef __attribute__((ext_vector_type(8))) short short8;
typedef __attribute__((ext_vector_type(4))) float floatx4;
typedef unsigned long long ull;

__device__ __forceinline__ float sigf(float x) { return 1.f / (1.f + __expf(-x)); }
__device__ __forceinline__ float tanh_f(float x) {
    float e = __expf(2.f * x);
    return 1.f - 2.f / (e + 1.f);
}
__device__ __forceinline__ unsigned short f2b(float x) {   // fp32 -> bf16 RNE
    unsigned u = __float_as_uint(x);
    unsigned r = (u + 0x7FFFu + ((u >> 16) & 1u)) >> 16;
    return (unsigned short)r;
}

// RELAXED agent-scope atomics only (acquire/release emit buffer_inv/wbl2 on
// gfx950 and trash the XCD L2). Cross-block payloads are {epoch|data} ull
// words polled directly (data+readiness in one MALL round trip), batch-polled.
// R15: enc_all's exchange VOLUME is the per-step cost driver (3.7us/step vs
// pyr's 1.6 with the same 1-RT protocol; enc reads 32KB/block/step, 7.7MB/step
// aggregate, ~150MB missing to HBM). This round halves it structurally:
// 30 groups x 8 frames, 8 dim-slices x 64 dims, 512-thread blocks. Per-thread
// weight load unchanged (160 VGPR), per-wave MFMA structure identical (A-frag
// frames 8..15 zero-padded once). Poll words/thread 16->4, producers/group
// 16->8, c-state in a register, h-publish via lane-pair shfl.
__device__ __forceinline__ float gld(const float* p) {
    return __hip_atomic_load(p, __ATOMIC_RELAXED, __HIP_MEMORY_SCOPE_AGENT);
}
__device__ __forceinline__ void gst(float* p, float v) {
    __hip_atomic_store(p, v, __ATOMIC_RELAXED, __HIP_MEMORY_SCOPE_AGENT);
}
__device__ __forceinline__ ull gldll(const ull* p) {
    return __hip_atomic_load(p, __ATOMIC_RELAXED, __HIP_MEMORY_SCOPE_AGENT);
}
__device__ __forceinline__ void gstll(ull* p, ull v) {
    __hip_atomic_store(p, v, __ATOMIC_RELAXED, __HIP_MEMORY_SCOPE_AGENT);
}
__device__ __forceinline__ ull packfe(float d, int ep) {
    return ((ull)(unsigned)ep << 32) | (ull)__float_as_uint(d);
}
__device__ __forceinline__ float lowf(ull v) { return __uint_as_float((unsigned)v); }

// ---------------------------------------------------------------------------
// init: zero [hbufF(245760f) | hp1(4096) | hp2(4096) | hdec(2048)] = 256000 f
// ---------------------------------------------------------------------------
__global__ void init_k(float* __restrict__ ws) {
    for (int i = blockIdx.x * blockDim.x + threadIdx.x; i < 256000; i += gridDim.x * blockDim.x)
        ws[i] = 0.f;
}

// ---------------------------------------------------------------------------
// Encoder R15: 240 blocks x 512 thr; group fg=bid>>3 (8 frames), slice
// ds=bid&7 (64 h-dims). Exchange buffer [2][30][2048] {epoch|bf16x2}:
// word widx = (d>>5)*128 + f*16 + ((d>>3)&3)*4 + ((d>>1)&3) carries h-dims
// (d, d+1) of frame f. Consumer decodes widx -> act2 int image. A-frag rows
// (frames) 8..15 are zero (one-time memset).
// ---------------------------------------------------------------------------
__global__ void __launch_bounds__(512, 1) enc_all(
    const float* __restrict__ data,
    const float* __restrict__ Wih, const float* __restrict__ Whh,
    const float* __restrict__ bih, const float* __restrict__ bhh,
    ull* __restrict__ hbufF,        // [2][30][2048] {epoch|bf16x2}
    float* __restrict__ henc)       // [240][512] fp32 final h
{
    __shared__ short act2[20 * 64 * 8];   // 16 h-tiles + 4 x-tiles; rows f>=8 zero
    __shared__ float gw[8][32 * 21];      // per wave: 32 gate-rows x 21 (16f+pad5)
    __shared__ float biasL[256];

    const int tid = threadIdx.x;
    const int fg = blockIdx.x >> 3, ds = blockIdx.x & 7;
    const int w = tid >> 6, lane = tid & 63;
    const int n = lane & 15, q = lane >> 4;
    const int ef = tid >> 6, edp = tid & 63;   // elementwise: frame, dim

    // weights: wave w covers block-rows rr = w*32 + nt*16 + n (256 rows total)
    short8 bfrag[2][20];
#pragma unroll
    for (int nt = 0; nt < 2; ++nt) {
        int rr = w * 32 + nt * 16 + n;
        int g = rr >> 6, dp = rr & 63;
        int grow = g * 512 + ds * 64 + dp;
#pragma unroll
        for (int kt = 0; kt < 20; ++kt) {
            int k0 = kt * 32 + q * 8;
            const float* src = (k0 < 512) ? (Whh + (size_t)grow * 512 + k0)
                                          : (Wih + (size_t)grow * 128 + (k0 - 512));
            float4 lo = *(const float4*)src;
            float4 hi = *(const float4*)(src + 4);
            short8 bf;
            bf[0] = (short)f2b(lo.x); bf[1] = (short)f2b(lo.y);
            bf[2] = (short)f2b(lo.z); bf[3] = (short)f2b(lo.w);
            bf[4] = (short)f2b(hi.x); bf[5] = (short)f2b(hi.y);
            bf[6] = (short)f2b(hi.z); bf[7] = (short)f2b(hi.w);
            bfrag[nt][kt] = bf;
        }
    }
    if (tid < 256) {
        int g = tid >> 6, dp = tid & 63;
        int grow = g * 512 + ds * 64 + dp;
        biasL[tid] = bih[grow] + bhh[grow];
    }
    unsigned* a2u = (unsigned*)act2;
    for (int i = tid; i < 5120; i += 512) a2u[i] = 0;   // one-time: rows f>=8 stay 0
    __syncthreads();

    float creg = 0.f;    // c-state for (ef, edp) lives in a register

    for (int t = 0; t < 64; ++t) {
        // x prefetch FIRST (no h dep): frame ef, dim pair kx
        const int kx = 2 * edp;                    // 0..126
        const float* xs = data + ((size_t)t * 240 + fg * 8 + ef) * 128 + kx;
        float2 xv = *(const float2*)xs;

        // h gather: batch-poll 4 {epoch|bf16x2} words (ONE MALL window)
        {
            const ull* hsrc = hbufF + (size_t)((t & 1) * 30 + fg) * 2048;
            ull v[4];
            for (;;) {
                bool ok = true;
#pragma unroll
                for (int k2 = 0; k2 < 4; ++k2) {
                    v[k2] = gldll(hsrc + tid + 512 * k2);
                    ok &= ((int)(v[k2] >> 32) == t);
                }
                if (ok) break;
                __builtin_amdgcn_s_sleep(1);
            }
#pragma unroll
            for (int k2 = 0; k2 < 4; ++k2) {
                int widx = tid + 512 * k2;
                int kt = widx >> 7, r = widx & 127;
                int f = r >> 4, qq = (r >> 2) & 3, e2 = r & 3;
                a2u[(kt * 64 + f + 16 * qq) * 4 + e2] = (unsigned)v[k2];
            }
        }
        {   // x into act2 (tiles 16..19), 2 bf16 per thread
            int kt2 = 16 + (kx >> 5), qq = (kx >> 3) & 3;
            unsigned px = (unsigned)f2b(xv.x) | ((unsigned)f2b(xv.y) << 16);
            a2u[(kt2 * 64 + ef + 16 * qq) * 4 + ((kx & 7) >> 1)] = px;
        }
        __syncthreads();

        floatx4 acc0 = {0.f, 0.f, 0.f, 0.f};
        floatx4 acc1 = {0.f, 0.f, 0.f, 0.f};
#pragma unroll
        for (int kt = 0; kt < 20; ++kt) {
            short8 a = *(short8*)&act2[(kt * 64 + lane) * 8];
            acc0 = __builtin_amdgcn_mfma_f32_16x16x32_bf16(a, bfrag[0][kt], acc0, 0, 0, 0);
            acc1 = __builtin_amdgcn_mfma_f32_16x16x32_bf16(a, bfrag[1][kt], acc1, 0, 0, 0);
        }
        *(floatx4*)&gw[w][(0 * 16 + n) * 21 + 4 * q] = acc0;
        *(floatx4*)&gw[w][(1 * 16 + n) * 21 + 4 * q] = acc1;
        __syncthreads();

        // elementwise: thread (ef, edp); gate g at block-row rr = g*64 + edp
        float g0, g1, g2v, g3;
        {
            int rr0 = 0 * 64 + edp, rr1 = 1 * 64 + edp, rr2 = 2 * 64 + edp, rr3 = 3 * 64 + edp;
            g0 = gw[rr0 >> 5][(rr0 & 31) * 21 + ef] + biasL[rr0];
            g1 = gw[rr1 >> 5][(rr1 & 31) * 21 + ef] + biasL[rr1];
            g2v = gw[rr2 >> 5][(rr2 & 31) * 21 + ef] + biasL[rr2];
            g3 = gw[rr3 >> 5][(rr3 & 31) * 21 + ef] + biasL[rr3];
        }
        float cn = sigf(g1) * creg + sigf(g0) * tanh_f(g2v);
        float hn = sigf(g3) * tanh_f(cn);
        creg = cn;
        if (t == 63)
            gst(&henc[(size_t)(fg * 8 + ef) * 512 + ds * 64 + edp], hn);

        // publish: even-dim lanes pack (hn, partner) into one word
        float hnn = __shfl_xor(hn, 1);
        if ((edp & 1) == 0) {
            int d = ds * 64 + edp;
            unsigned pv = (unsigned)f2b(hn) | ((unsigned)f2b(hnn) << 16);
            int widx = (d >> 5) * 128 + ef * 16 + ((d >> 3) & 3) * 4 + ((d >> 1) & 3);
            gstll(hbufF + (size_t)(((t + 1) & 1) * 30 + fg) * 2048 + widx,
                  ((ull)(unsigned)(t + 1) << 32) | (ull)pv);
        }
        __syncthreads();
    }
}

// ---------------------------------------------------------------------------
// xp GEMM stage 1 (A = henc), F/B pair fused (unchanged).
// ---------------------------------------------------------------------------
__global__ void __launch_bounds__(256) gemm_xp2(
    const float* __restrict__ A, int M, int K, int halfgrid,
    const float* __restrict__ WvF, const float* __restrict__ baF,
    const float* __restrict__ bbF, float* __restrict__ CF,
    const float* __restrict__ WvB, const float* __restrict__ baB,
    const float* __restrict__ bbB, float* __restrict__ CB)
{
    __shared__ float At[16][66];
    __shared__ float Wt[128][66];
    const int tid = threadIdx.x;
    int bgl = blockIdx.x;
    const int rev = (bgl >= halfgrid) ? 1 : 0;
    if (rev) bgl -= halfgrid;
    const float* Wv = rev ? WvB : WvF;
    const float* ba = rev ? baB : baF;
    const float* bb = rev ? bbB : bbF;
    float* C        = rev ? CB : CF;

    const int nt = bgl & 15, mt = bgl >> 4;
    const int rp = tid >> 2, fq = tid & 3;
    const int lr0 = 2 * rp, lr1 = lr0 + 1;
    const int n0 = nt * 128 + lr0, n1 = n0 + 1;

    float acc0[4], acc1[4];
    {
        float b0 = ba[n0] + bb[n0], b1 = ba[n1] + bb[n1];
#pragma unroll
        for (int j = 0; j < 4; ++j) { acc0[j] = b0; acc1[j] = b1; }
    }

    for (int kt = 0; kt < K; kt += 64) {
        {
            int f = tid >> 4, c4 = tid & 15;
            int m = mt * 16 + f;
            float4 v = make_float4(0.f, 0.f, 0.f, 0.f);
            if (m < M) {
                int ar = rev ? (M - 1 - m) : m;
                v = ((const float4*)(A + (size_t)ar * K + kt))[c4];
            }
            At[f][c4 * 4 + 0] = v.x; At[f][c4 * 4 + 1] = v.y;
            At[f][c4 * 4 + 2] = v.z; At[f][c4 * 4 + 3] = v.w;
        }
        for (int i = tid; i < 2048; i += 256) {
            int lr = i >> 4, c4 = i & 15;
            float4 v = ((const float4*)(Wv + (size_t)(nt * 128 + lr) * K + kt))[c4];
            Wt[lr][c4 * 4 + 0] = v.x; Wt[lr][c4 * 4 + 1] = v.y;
            Wt[lr][c4 * 4 + 2] = v.z; Wt[lr][c4 * 4 + 3] = v.w;
        }
        __syncthreads();
        const float2* w0p = (const float2*)(&Wt[lr0][0]);
        const float2* w1p = (const float2*)(&Wt[lr1][0]);
#pragma unroll 8
        for (int kh = 0; kh < 32; ++kh) {
            float2 w0 = w0p[kh], w1 = w1p[kh];
#pragma unroll
            for (int j = 0; j < 4; ++j) {
                float2 av = ((const float2*)(&At[4 * fq + j][0]))[kh];
                acc0[j] += w0.x * av.x + w0.y * av.y;
                acc1[j] += w1.x * av.x + w1.y * av.y;
            }
        }
        __syncthreads();
    }
#pragma unroll
    for (int j = 0; j < 4; ++j) {
        int m = mt * 16 + 4 * fq + j;
        if (m < M) {
            C[(size_t)m * 2048 + n0] = acc0[j];
            C[(size_t)m * 2048 + n1] = acc1[j];
        }
    }
}

// ---------------------------------------------------------------------------
// xp GEMM stage 2 reading the virtual x2 directly from f1/b1o (unchanged).
// ---------------------------------------------------------------------------
__global__ void __launch_bounds__(256) gemm_x2(
    const float* __restrict__ f1, const float* __restrict__ b1o,
    int M, int K, int halfgrid,
    const float* __restrict__ WvF, const float* __restrict__ baF,
    const float* __restrict__ bbF, float* __restrict__ CF,
    const float* __restrict__ WvB, const float* __restrict__ baB,
    const float* __restrict__ bbB, float* __restrict__ CB)
{
    __shared__ float At[16][66];
    __shared__ float Wt[128][66];
    const int tid = threadIdx.x;
    int bgl = blockIdx.x;
    const int rev = (bgl >= halfgrid) ? 1 : 0;
    if (rev) bgl -= halfgrid;
    const float* Wv = rev ? WvB : WvF;
    const float* ba = rev ? baB : baF;
    const float* bb = rev ? bbB : bbF;
    float* C        = rev ? CB : CF;

    const int nt = bgl & 15, mt = bgl >> 4;
    const int rp = tid >> 2, fq = tid & 3;
    const int lr0 = 2 * rp, lr1 = lr0 + 1;
    const int n0 = nt * 128 + lr0, n1 = n0 + 1;

    float acc0[4], acc1[4];
    {
        float b0 = ba[n0] + bb[n0], b1 = ba[n1] + bb[n1];
#pragma unroll
        for (int j = 0; j < 4; ++j) { acc0[j] = b0; acc1[j] = b1; }
    }

    for (int kt = 0; kt < K; kt += 64) {
        {
            int f = tid >> 4, c4 = tid & 15;
            int m = mt * 16 + f;
            float4 v = make_float4(0.f, 0.f, 0.f, 0.f);
            if (m < M) {
                int ar = rev ? (M - 1 - m) : m;
                int seg = kt >> 9;              // 0..3 (K=2048)
                int r = (kt & 511) + 4 * c4;    // within 512-block
                const float* src = (seg & 1) ? b1o : f1;
                int srow = 2 * ar + (seg >> 1);
                v = *(const float4*)&src[(size_t)srow * 512 + r];
            }
            At[f][c4 * 4 + 0] = v.x; At[f][c4 * 4 + 1] = v.y;
            At[f][c4 * 4 + 2] = v.z; At[f][c4 * 4 + 3] = v.w;
        }
        for (int i = tid; i < 2048; i += 256) {
            int lr = i >> 4, c4 = i & 15;
            float4 v = ((const float4*)(Wv + (size_t)(nt * 128 + lr) * K + kt))[c4];
            Wt[lr][c4 * 4 + 0] = v.x; Wt[lr][c4 * 4 + 1] = v.y;
            Wt[lr][c4 * 4 + 2] = v.z; Wt[lr][c4 * 4 + 3] = v.w;
        }
        __syncthreads();
        const float2* w0p = (const float2*)(&Wt[lr0][0]);
        const float2* w1p = (const float2*)(&Wt[lr1][0]);
#pragma unroll 8
        for (int kh = 0; kh < 32; ++kh) {
            float2 w0 = w0p[kh], w1 = w1p[kh];
#pragma unroll
            for (int j = 0; j < 4; ++j) {
                float2 av = ((const float2*)(&At[4 * fq + j][0]))[kh];
                acc0[j] += w0.x * av.x + w0.y * av.y;
                acc1[j] += w1.x * av.x + w1.y * av.y;
            }
        }
        __syncthreads();
    }
#pragma unroll
    for (int j = 0; j < 4; ++j) {
        int m = mt * 16 + 4 * fq + j;
        if (m < M) {
            C[(size_t)m * 2048 + n0] = acc0[j];
            C[(size_t)m * 2048 + n1] = acc1[j];
        }
    }
}

// ---------------------------------------------------------------------------
// Pyramidal bi-LSTM (unchanged from R14).
// ---------------------------------------------------------------------------
__global__ void __launch_bounds__(256, 1) pyr_rec(
    const float* __restrict__ xpF, const float* __restrict__ xpB,
    const float* __restrict__ WhhF, const float* __restrict__ WhhB,
    ull* __restrict__ hp,      // [dir][2][512]
    float* __restrict__ outF, float* __restrict__ outB,
    int steps)
{
    const int tid = threadIdx.x;
    const int dir = blockIdx.x >> 6, blk = blockIdx.x & 63;
    const float* xp  = dir ? xpB : xpF;
    const float* Whh = dir ? WhhB : WhhF;
    float* outp = dir ? outB : outF;
    ull* hpd = hp + (size_t)dir * 1024;

    __shared__ __align__(16) float hcur[512];
    __shared__ float gv[32];

    const int row = tid >> 3, seg = tid & 7;   // 32 rows x 8 segs
    const int grow = (row >> 3) * 512 + blk * 8 + (row & 7);
    float4 wl4[16];
#pragma unroll
    for (int j = 0; j < 16; ++j)
        wl4[j] = *(const float4*)&Whh[(size_t)grow * 512 + 4 * seg + 32 * j];

    float creg = 0.f;
    __syncthreads();

    for (int t = 0; t < steps; ++t) {
        float xg = 0.f;
        if (seg == 0) xg = xp[(size_t)t * 2048 + grow];   // prefetch (no h dep)
        {
            const ull* base = hpd + (size_t)(t & 1) * 512;
            ull v0 = gldll(base + tid), v1 = gldll(base + tid + 256);
            while (((int)(v0 >> 32) != t) | ((int)(v1 >> 32) != t)) {
                __builtin_amdgcn_s_sleep(1);
                v0 = gldll(base + tid);
                v1 = gldll(base + tid + 256);
            }
            hcur[tid]       = lowf(v0);
            hcur[tid + 256] = lowf(v1);
        }
        __syncthreads();

        float a = 0.f;
#pragma unroll
        for (int j = 0; j < 16; ++j) {
            float4 w = wl4[j];
            float4 h4 = *(const float4*)&hcur[4 * seg + 32 * j];
            a += w.x*h4.x + w.y*h4.y + w.z*h4.z + w.w*h4.w;
        }
        a += __shfl_xor(a, 1);
        a += __shfl_xor(a, 2);
        a += __shfl_xor(a, 4);
        if (seg == 0) gv[row] = a + xg;
        __syncthreads();

        if (tid < 8) {
            float i_ = sigf(gv[tid]), f_ = sigf(gv[8 + tid]);
            float g_ = tanh_f(gv[16 + tid]), o_ = sigf(gv[24 + tid]);
            creg = f_ * creg + i_ * g_;
            float hn = o_ * tanh_f(creg);
            int d = blk * 8 + tid;
            gstll(&hpd[((t + 1) & 1) * 512 + d], packfe(hn, t + 1));
            int row2 = dir ? (steps - 1 - t) : t;
            outp[(size_t)row2 * 512 + d] = hn;
        }
        __syncthreads();
    }
}

// ---------------------------------------------------------------------------
// precompute M^T directly from f2/b2o; block 0 publishes hdec epoch-0.
// ---------------------------------------------------------------------------
__global__ void __launch_bounds__(256) precomp_M(
    const float* __restrict__ comb_W,   // [512][1032]
    const float* __restrict__ f2,       // [60][512]
    const float* __restrict__ b2o,      // [60][512]
    float* __restrict__ MgT,            // [60][512]
    ull* __restrict__ hdec_p)           // [2][512]
{
    __shared__ float cw[8 * 1024];      // 32 KB: comb_W rows d0..d0+8, cols 8..1032
    const int tid = threadIdx.x, d0 = blockIdx.x * 8;
    for (int i = tid; i < 2048; i += 256) {
        int r = i >> 8, c4 = i & 255;
        float4 v = *(const float4*)&comb_W[(size_t)(d0 + r) * 1032 + 8 + 4 * c4];
        *(float4*)&cw[r * 1024 + 4 * c4] = v;
    }
    if (blockIdx.x == 0) {
        for (int i = tid; i < 512; i += 256)
            hdec_p[i] = packfe(f2[59 * 512 + i], 0);
    }
    __syncthreads();
    for (int o = tid; o < 480; o += 256) {
        int dl = o / 60, j = o % 60;
        const float4* cp0 = (const float4*)&cw[dl * 1024];          // k 0..511
        const float4* cp1 = (const float4*)&cw[dl * 1024 + 512];    // k 512..1023
        const float4* xf = (const float4*)(f2 + (size_t)j * 512);
        const float4* xb = (const float4*)(b2o + (size_t)j * 512);
        float a = 0.f;
#pragma unroll 4
        for (int k = 0; k < 128; ++k) {
            float4 w = cp0[k], x = xf[k];
            a += w.x * x.x + w.y * x.y + w.z * x.z + w.w * x.w;
        }
#pragma unroll 4
        for (int k = 0; k < 128; ++k) {
            float4 w = cp1[k], x = xb[k];
            a += w.x * x.x + w.y * x.y + w.z * x.z + w.w * x.w;
        }
        MgT[(size_t)j * 512 + (d0 + dl)] = a;
    }
}

// ---------------------------------------------------------------------------
// Decoder (unchanged from R11): 64 blocks x 512 threads, register weights,
// shuffle reductions, conflict-free LDS mappings, 1-word/thread h poll.
// ---------------------------------------------------------------------------
__global__ void __launch_bounds__(512, 1) dec_k(
    const float* __restrict__ attn_W, const float* __restrict__ attn_b,
    const float* __restrict__ comb_W, const float* __restrict__ comb_b,
    const float* __restrict__ gWih, const float* __restrict__ gWhh,
    const float* __restrict__ gbih, const float* __restrict__ gbhh,
    const float* __restrict__ outW, const float* __restrict__ outb,
    const float* __restrict__ MgT,  // [60][512]
    ull* __restrict__ hdec_p,       // [2][512]
    float* __restrict__ dout)
{
    const int tid = threadIdx.x, bid = blockIdx.x;   // 64 blocks x 512 thr
    const int lane = tid & 63, wv = tid >> 6;
    const int dbase = bid * 8;

    __shared__ float M2T[68][512];                   // rows: [M(60) | Minp(8)]
    __shared__ __align__(16) float hL[520];          // h(512) + pad
    __shared__ __align__(16) float xl[512];          // o
    __shared__ __align__(16) float awx[68];          // [aw(60); inp(8)]
    __shared__ float zd[8], zh[64];
    __shared__ float ghl[24], gil[24];
    __shared__ float biasg[24], biasi[24];
    __shared__ float cbL[512];
    __shared__ float attnbL[64], outbL[8];

    // row/seg partitions
    const int rg = tid >> 4, sg = tid & 15;   // gh/gi: 24(32) rows x 16 segs
    const int rz = tid >> 3, szz = tid & 7;   // z_h: 60(64) rows x 8 segs

    // ---- weights to registers (interleaved k-mappings) ----
    float4 wo2[2];                  // logits row wv: k = 4*lane + 256*i
    float4 wg8[8], wi8[8];          // gh/gi row rg:  k = 4*sg + 64*i
    float4 wzh[16];                 // z_h row rz:    k = 4*szz + 32*i
    float4 wip[2];                  // z inp-part (row tid<60)
    {
        const float* wp = outW + (size_t)wv * 512 + 4 * lane;
        wo2[0] = *(const float4*)wp;
        wo2[1] = *(const float4*)(wp + 256);
    }
    {
        int rr = (rg < 24) ? rg : 23;
        size_t grow = (size_t)((rr >> 3) * 512 + dbase + (rr & 7)) * 512 + 4 * sg;
#pragma unroll
        for (int i = 0; i < 8; ++i) {
            wg8[i] = *(const float4*)&gWhh[grow + 64 * i];
            wi8[i] = *(const float4*)&gWih[grow + 64 * i];
        }
    }
    {
        int rr = (rz < 60) ? rz : 59;
        size_t base = (size_t)rr * 520 + 8 + 4 * szz;
#pragma unroll
        for (int i = 0; i < 16; ++i)
            wzh[i] = *(const float4*)&attn_W[base + 32 * i];
    }
    {
        int rr = (tid < 60) ? tid : 59;
        wip[0] = *(const float4*)&attn_W[(size_t)rr * 520 + 0];
        wip[1] = *(const float4*)&attn_W[(size_t)rr * 520 + 4];
    }
    if (tid < 24) {
        int g2 = (tid >> 3) * 512 + dbase + (tid & 7);
        biasg[tid] = gbhh[g2];
        biasi[tid] = gbih[g2];
    }
    cbL[tid] = comb_b[tid];
    if (tid < 64) attnbL[tid] = (tid < 60) ? attn_b[tid] : 0.f;
    if (tid < 8) outbL[tid] = outb[tid];
    // M2T rows 0..59 from MgT (coalesced), rows 60..67 = comb_W cols 0..8
    for (int i = tid; i < 7680; i += 512) {
        int j = i >> 7, c4 = i & 127;
        *(float4*)&M2T[j][4 * c4] = *(const float4*)&MgT[(size_t)j * 512 + 4 * c4];
    }
    for (int i = tid; i < 4096; i += 512) {
        int r = i >> 3, c = i & 7;
        M2T[60 + c][r] = comb_W[(size_t)r * 1032 + c];
    }
    __syncthreads();

    for (int s = 0; s < 30; ++s) {
        // ---- cross-block hop: h (slot s&1, epoch s), 1 word/thread ----
        {
            const ull* hs = hdec_p + (size_t)(s & 1) * 512;
            ull v0 = gldll(hs + tid);
            while ((int)(v0 >> 32) != s) {
                __builtin_amdgcn_s_sleep(1);
                v0 = gldll(hs + tid);
            }
            hL[tid] = lowf(v0);
        }
        __syncthreads();

        // ---- phase A: three h-matvec partials + shuffle reductions ----
        {   // logits: one wave per row, contiguous 16B-stride reads
            float a = 0.f;
            float4 h0 = *(const float4*)&hL[4 * lane];
            float4 h1 = *(const float4*)&hL[4 * lane + 256];
            a += wo2[0].x*h0.x + wo2[0].y*h0.y + wo2[0].z*h0.z + wo2[0].w*h0.w;
            a += wo2[1].x*h1.x + wo2[1].y*h1.y + wo2[1].z*h1.z + wo2[1].w*h1.w;
#pragma unroll
            for (int off = 32; off; off >>= 1) a += __shfl_xor(a, off);
            if (lane == 0) zd[wv] = a;
        }
        {   // gh: 16 segs, k = 4*sg + 64*i
            float a = 0.f;
#pragma unroll
            for (int i = 0; i < 8; ++i) {
                float4 w = wg8[i];
                float4 h4 = *(const float4*)&hL[4 * sg + 64 * i];
                a += w.x*h4.x + w.y*h4.y + w.z*h4.z + w.w*h4.w;
            }
            a += __shfl_xor(a, 1); a += __shfl_xor(a, 2);
            a += __shfl_xor(a, 4); a += __shfl_xor(a, 8);
            if (sg == 0 && rg < 24) ghl[rg] = a;
        }
        {   // z_h: 8 segs, k = 4*szz + 32*i
            float a = 0.f;
#pragma unroll
            for (int i = 0; i < 16; ++i) {
                float4 w = wzh[i];
                float4 h4 = *(const float4*)&hL[4 * szz + 32 * i];
                a += w.x*h4.x + w.y*h4.y + w.z*h4.z + w.w*h4.w;
            }
            a += __shfl_xor(a, 1); a += __shfl_xor(a, 2); a += __shfl_xor(a, 4);
            if (szz == 0 && rz < 60) zh[rz] = a;
        }
        __syncthreads();

        // ---- phase BC (wave 0): inp -> z finalize -> softmax60 ----
        if (wv == 0) {
            if (lane < 8) {
                float v;
                if (s > 0) {
                    float a = zd[lane] + outbL[lane];
                    float m = a;
                    m = fmaxf(m, __shfl_xor(m, 1));
                    m = fmaxf(m, __shfl_xor(m, 2));
                    m = fmaxf(m, __shfl_xor(m, 4));
                    float e = __expf(a - m);
                    float ss2 = e;
                    ss2 += __shfl_xor(ss2, 1);
                    ss2 += __shfl_xor(ss2, 2);
                    ss2 += __shfl_xor(ss2, 4);
                    v = a - m - __logf(ss2);
                    if (bid == 0) dout[(s - 1) * 8 + lane] = v;
                } else {
                    v = (lane == 7) ? 1.f : 0.f;
                }
                awx[60 + lane] = v;
            }
            // z = zh + b + attn_W[:,0:8] @ inp  (same-wave LDS ordering)
            float z = -1e30f;
            if (lane < 60) {
                z = zh[lane] + attnbL[lane]
                  + wip[0].x * awx[60] + wip[0].y * awx[61]
                  + wip[0].z * awx[62] + wip[0].w * awx[63]
                  + wip[1].x * awx[64] + wip[1].y * awx[65]
                  + wip[1].z * awx[66] + wip[1].w * awx[67];
            }
            float m = z;
#pragma unroll
            for (int off = 32; off; off >>= 1) m = fmaxf(m, __shfl_xor(m, off));
            float e = (lane < 60) ? __expf(z - m) : 0.f;
            float ss2 = e;
#pragma unroll
            for (int off = 32; off; off >>= 1) ss2 += __shfl_xor(ss2, off);
            if (lane < 60) awx[lane] = e / ss2;
        }
        __syncthreads();

        // ---- phase E: o = relu(M2T^T @ [aw; inp] + comb_b), 1 dim/thread ----
        {
            float a = cbL[tid];
#pragma unroll 4
            for (int k = 0; k < 68; ++k)
                a += M2T[k][tid] * awx[k];
            xl[tid] = fmaxf(a, 0.f);
        }
        __syncthreads();

        // ---- phase F: gi = gWih @ o, k = 4*sg + 64*i ----
        {
            float a = 0.f;
#pragma unroll
            for (int i = 0; i < 8; ++i) {
                float4 w = wi8[i];
                float4 o4 = *(const float4*)&xl[4 * sg + 64 * i];
                a += w.x*o4.x + w.y*o4.y + w.z*o4.z + w.w*o4.w;
            }
            a += __shfl_xor(a, 1); a += __shfl_xor(a, 2);
            a += __shfl_xor(a, 4); a += __shfl_xor(a, 8);
            if (sg == 0 && rg < 24) gil[rg] = a;
        }
        __syncthreads();

        // ---- phase G: GRU combine + publish (8 threads) ----
        if (tid < 8) {
            float gh0 = biasg[tid] + ghl[tid];
            float gh1 = biasg[8 + tid] + ghl[8 + tid];
            float gh2 = biasg[16 + tid] + ghl[16 + tid];
            float gi0 = biasi[tid] + gil[tid];
            float gi1 = biasi[8 + tid] + gil[8 + tid];
            float gi2 = biasi[16 + tid] + gil[16 + tid];
            float r_ = sigf(gi0 + gh0);
            float z_ = sigf(gi1 + gh1);
            float n_ = tanh_f(gi2 + r_ * gh2);
            float hnew = (1.f - z_) * n_ + z_ * hL[dbase + tid];
            gstll(&hdec_p[(size_t)((s + 1) & 1) * 512 + dbase + tid], packfe(hnew, s + 1));
        }
        __syncthreads();   // protect hL/awx/xl before next-step overwrite
    }

    // epilogue: logits for s=29 (block 0 only)
    if (bid == 0) {
        {
            const ull* hs = hdec_p + (size_t)(30 & 1) * 512;
            ull v0 = gldll(hs + tid);
            while ((int)(v0 >> 32) != 30) {
                __builtin_amdgcn_s_sleep(1);
                v0 = gldll(hs + tid);
            }
            hL[tid] = lowf(v0);
        }
        __syncthreads();
        {
            float a = 0.f;
            float4 h0 = *(const float4*)&hL[4 * lane];
            float4 h1 = *(const float4*)&hL[4 * lane + 256];
            a += wo2[0].x*h0.x + wo2[0].y*h0.y + wo2[0].z*h0.z + wo2[0].w*h0.w;
            a += wo2[1].x*h1.x + wo2[1].y*h1.y + wo2[1].z*h1.z + wo2[1].w*h1.w;
#pragma unroll
            for (int off = 32; off; off >>= 1) a += __shfl_xor(a, off);
            if (lane == 0) zd[wv] = a;
        }
        __syncthreads();
        if (tid < 8) {
            float a = zd[tid] + outbL[tid];
            float m = a;
            m = fmaxf(m, __shfl_xor(m, 1));
            m = fmaxf(m, __shfl_xor(m, 2));
            m = fmaxf(m, __shfl_xor(m, 4));
            float e = __expf(a - m);
            float ss2 = e;
            ss2 += __shfl_xor(ss2, 1);
            ss2 += __shfl_xor(ss2, 2);
            ss2 += __shfl_xor(ss2, 4);
            dout[29 * 8 + tid] = a - m - __logf(ss2);
        }
    }
}

// ---------------------------------------------------------------------------
extern "C" void kernel_launch(void* const* d_in, const int* in_sizes, int n_in,
                              void* d_out, int out_size, void* d_ws, size_t ws_size,
                              hipStream_t stream) {
    (void)in_sizes; (void)n_in; (void)out_size; (void)ws_size;
    const float* data    = (const float*)d_in[0];
    const float* enc_Wih = (const float*)d_in[1];
    const float* enc_Whh = (const float*)d_in[2];
    const float* enc_bih = (const float*)d_in[3];
    const float* enc_bhh = (const float*)d_in[4];
    const float* p1f_Wih = (const float*)d_in[5];
    const float* p1f_Whh = (const float*)d_in[6];
    const float* p1f_bih = (const float*)d_in[7];
    const float* p1f_bhh = (const float*)d_in[8];
    const float* p1b_Wih = (const float*)d_in[9];
    const float* p1b_Whh = (const float*)d_in[10];
    const float* p1b_bih = (const float*)d_in[11];
    const float* p1b_bhh = (const float*)d_in[12];
    const float* p2f_Wih = (const float*)d_in[13];
    const float* p2f_Whh = (const float*)d_in[14];
    const float* p2f_bih = (const float*)d_in[15];
    const float* p2f_bhh = (const float*)d_in[16];
    const float* p2b_Wih = (const float*)d_in[17];
    const float* p2b_Whh = (const float*)d_in[18];
    const float* p2b_bih = (const float*)d_in[19];
    const float* p2b_bhh = (const float*)d_in[20];
    const float* attn_W  = (const float*)d_in[21];
    const float* attn_b  = (const float*)d_in[22];
    const float* comb_W  = (const float*)d_in[23];
    const float* comb_b  = (const float*)d_in[24];
    const float* gru_Wih = (const float*)d_in[25];
    const float* gru_Whh = (const float*)d_in[26];
    const float* gru_bih = (const float*)d_in[27];
    const float* gru_bhh = (const float*)d_in[28];
    const float* out_W   = (const float*)d_in[29];
    const float* out_b   = (const float*)d_in[30];

    float* ws = (float*)d_ws;
    // zeroed region [0 .. 256000)
    ull* hbufF   = (ull*)ws;                 // 245760 floats = [2][30][2048] ull
    ull* hp1     = (ull*)(ws + 245760);      // 4096 floats = [2][2][512] ull
    ull* hp2     = (ull*)(ws + 249856);      // 4096 floats
    ull* hdec_p  = (ull*)(ws + 253952);      // 2048 floats -> end 256000
    // non-zeroed scratch
    float* henc  = ws + 256000;              // 122880
    float* xp1f  = ws + 378880;              // 245760
    float* xp1b  = ws + 624640;              // 245760
    float* f1    = ws + 870400;              // 61440
    float* b1o   = ws + 931840;              // 61440
    float* xp2f  = ws + 993280;              // 122880
    float* xp2b  = ws + 1116160;             // 122880
    float* f2    = ws + 1239040;             // 30720
    float* b2o   = ws + 1269760;             // 30720
    float* MgT   = ws + 1300480;             // 30720 -> end 1331200

    init_k<<<256, 256, 0, stream>>>(ws);

    enc_all<<<240, 512, 0, stream>>>(data, enc_Wih, enc_Whh, enc_bih, enc_bhh,
                                     hbufF, henc);
    gemm_xp2<<<256, 256, 0, stream>>>(henc, 120, 1024, 128,
                                      p1f_Wih, p1f_bih, p1f_bhh, xp1f,
                                      p1b_Wih, p1b_bih, p1b_bhh, xp1b);
    pyr_rec<<<128, 256, 0, stream>>>(xp1f, xp1b, p1f_Whh, p1b_Whh, hp1, f1, b1o, 120);
    gemm_x2<<<128, 256, 0, stream>>>(f1, b1o, 60, 2048, 64,
                                     p2f_Wih, p2f_bih, p2f_bhh, xp2f,
                                     p2b_Wih, p2b_bih, p2b_bhh, xp2b);
    pyr_rec<<<128, 256, 0, stream>>>(xp2f, xp2b, p2f_Whh, p2b_Whh, hp2, f2, b2o, 60);
    precomp_M<<<64, 256, 0, stream>>>(comb_W, f2, b2o, MgT, hdec_p);
    dec_k<<<64, 512, 0, stream>>>(attn_W, attn_b, comb_W, comb_b,
                                  gru_Wih, gru_Whh, gru_bih, gru_bhh,
                                  out_W, out_b, MgT, hdec_p,
                                  (float*)d_out);
}